// Round 5
// baseline (1899.703 us; speedup 1.0000x reference)
//
#include <hip/hip_runtime.h>

// ---------------------------------------------------------------------------
// GraphElementNetwork forward, bucketed path v5:
//  - v4 + register-pressure fix on edge passes: __launch_bounds__(256,4)
//    (VGPR <= 128 -> 4 waves/SIMD) and 2 edges/thread in passB (v4: 216 VGPR
//    -> 2 waves/SIMD -> 10% occupancy, latency-bound on H1 gathers).
// ---------------------------------------------------------------------------

#define NHB 256   // histogram / scatter blocks (1 per CU)
#define GSP 4     // slices per bucket in edge passes

// ============================ bucketing ====================================

__global__ void __launch_bounds__(256) k_chist(
    const int* __restrict__ DST, int* __restrict__ hist,
    int e, int nbkt, int shift, int epb)
{
    __shared__ int lh[512];
    for (int c = threadIdx.x; c < nbkt; c += blockDim.x) lh[c] = 0;
    __syncthreads();
    int b = blockIdx.x;
    int i0 = b * epb, i1 = min(i0 + epb, e);
    int nq = (i1 > i0) ? ((i1 - i0) >> 2) : 0;
    const int4* D4 = reinterpret_cast<const int4*>(DST + i0);
    for (int q = threadIdx.x; q < nq; q += blockDim.x) {
        int4 d = D4[q];
        atomicAdd(&lh[d.x >> shift], 1);
        atomicAdd(&lh[d.y >> shift], 1);
        atomicAdd(&lh[d.z >> shift], 1);
        atomicAdd(&lh[d.w >> shift], 1);
    }
    for (int i = i0 + 4 * nq + threadIdx.x; i < i1; i += blockDim.x)
        atomicAdd(&lh[DST[i] >> shift], 1);
    __syncthreads();
    for (int c = threadIdx.x; c < nbkt; c += blockDim.x)
        hist[(size_t)c * NHB + b] = lh[c];
}

__global__ void __launch_bounds__(256) k_scanA(
    int* __restrict__ hist, int* __restrict__ bktCnt)
{
    int c = blockIdx.x;
    int* row = hist + (size_t)c * NHB;
    __shared__ int part[256];
    int t = threadIdx.x;
    int v = row[t];
    part[t] = v;
    __syncthreads();
    for (int off = 1; off < 256; off <<= 1) {
        int x = 0;
        if (t >= off) x = part[t - off];
        __syncthreads();
        part[t] += x;
        __syncthreads();
    }
    if (t == 255) bktCnt[c] = part[255];
    row[t] = part[t] - v;
}

__global__ void __launch_bounds__(256) k_scanB(
    const int* __restrict__ bktCnt, int* __restrict__ base, int nbkt, int e)
{
    __shared__ int part[256];
    int t = threadIdx.x;
    int v[4];
    int sum = 0;
    #pragma unroll
    for (int u = 0; u < 4; ++u) {
        int idx = t * 4 + u;
        v[u] = (idx < nbkt) ? bktCnt[idx] : 0;
        sum += v[u];
    }
    part[t] = sum;
    __syncthreads();
    for (int off = 1; off < 256; off <<= 1) {
        int x = 0;
        if (t >= off) x = part[t - off];
        __syncthreads();
        part[t] += x;
        __syncthreads();
    }
    int run = (t == 0) ? 0 : part[t - 1];
    #pragma unroll
    for (int u = 0; u < 4; ++u) {
        int idx = t * 4 + u;
        if (idx < nbkt) base[idx] = run;
        run += v[u];
    }
    if (t == 0) base[nbkt] = e;
}

__global__ void __launch_bounds__(256) k_scatter(
    const int* __restrict__ DST, const int* __restrict__ SRC,
    const float* __restrict__ DIST, const float* __restrict__ EF,
    const int* __restrict__ hist, const int* __restrict__ base,
    float2* __restrict__ payA, float* __restrict__ ef_s,
    int e, int nbkt, int shift, int epb)
{
    __shared__ int loff[512];
    int b = blockIdx.x;
    for (int c = threadIdx.x; c < nbkt; c += blockDim.x)
        loff[c] = base[c] + hist[(size_t)c * NHB + b];
    __syncthreads();
    int i0 = b * epb, i1 = min(i0 + epb, e);
    if (i0 >= i1) return;
    int mask = (1 << shift) - 1;
    int nq = (i1 - i0) >> 2;
    const int4*   D4 = reinterpret_cast<const int4*>(DST + i0);
    const int4*   S4 = reinterpret_cast<const int4*>(SRC + i0);
    const float4* T4 = reinterpret_cast<const float4*>(DIST + i0);
    const float4* F4 = reinterpret_cast<const float4*>(EF + i0);
    for (int q = threadIdx.x; q < nq; q += blockDim.x) {
        int4 dv = D4[q];
        int4 sv = S4[q];
        float4 tv = T4[q];
        float4 fv = F4[q];
        #pragma unroll
        for (int u = 0; u < 4; ++u) {
            int d = (&dv.x)[u];
            int c = d >> shift;
            int pos = atomicAdd(&loff[c], 1);
            int sd = ((&sv.x)[u] << shift) | (d & mask);
            payA[pos] = make_float2(__int_as_float(sd), (&tv.x)[u]);
            ef_s[pos] = (&fv.x)[u];
        }
    }
    for (int i = i0 + 4 * nq + threadIdx.x; i < i1; i += blockDim.x) {
        int d = DST[i];
        int c = d >> shift;
        int pos = atomicAdd(&loff[c], 1);
        int sd = (SRC[i] << shift) | (d & mask);
        payA[pos] = make_float2(__int_as_float(sd), DIST[i]);
        ef_s[pos] = EF[i];
    }
}

// ============================ node encoder =================================

__global__ void __launch_bounds__(256) k_enc(
    const float* __restrict__ X, const float* __restrict__ W1,
    const float* __restrict__ B1, const float* __restrict__ W2,
    const float* __restrict__ B2, float* __restrict__ H0, int n)
{
    __shared__ float4 w1s[2048];
    for (int t = threadIdx.x; t < 2048; t += blockDim.x)
        w1s[t] = reinterpret_cast<const float4*>(W1)[t];
    __syncthreads();

    int i = blockIdx.x * blockDim.x + threadIdx.x;
    if (i >= n) return;

    const float4* xp = reinterpret_cast<const float4*>(X) + (size_t)i * 32;

    float acc[64];
    #pragma unroll
    for (int j = 0; j < 64; ++j) acc[j] = B1[j];

    for (int k4 = 0; k4 < 32; ++k4) {
        float4 xv = xp[k4];
        #pragma unroll
        for (int kk = 0; kk < 4; ++kk) {
            float x = (&xv.x)[kk];
            const float4* wrow = &w1s[(k4 * 4 + kk) * 16];
            #pragma unroll
            for (int j4 = 0; j4 < 16; ++j4) {
                float4 w = wrow[j4];
                acc[j4*4+0] = fmaf(x, w.x, acc[j4*4+0]);
                acc[j4*4+1] = fmaf(x, w.y, acc[j4*4+1]);
                acc[j4*4+2] = fmaf(x, w.z, acc[j4*4+2]);
                acc[j4*4+3] = fmaf(x, w.w, acc[j4*4+3]);
            }
        }
    }
    float o = B2[0];
    #pragma unroll
    for (int j = 0; j < 64; ++j)
        o = fmaf(fmaxf(acc[j], 0.f), W2[j], o);
    H0[i] = fmaxf(o, 0.f);
}

// ==================== bucketed edge passes (G-split) =======================
// partial layout: p[((c*GSP + g) << shift) + t]

__global__ void __launch_bounds__(256, 4) k_passA(
    const float2* __restrict__ payA, const float* __restrict__ H0,
    const int* __restrict__ base,
    float* __restrict__ pSum, float* __restrict__ pNum, int shift)
{
    __shared__ float lsum[256], lnum[256];
    int c = blockIdx.x / GSP, g = blockIdx.x % GSP;
    int bw = 1 << shift, mask = bw - 1;
    for (int t = threadIdx.x; t < bw; t += blockDim.x) { lsum[t] = 0.f; lnum[t] = 0.f; }
    __syncthreads();
    int b0 = base[c], len = base[c + 1] - b0;
    int i0 = b0 + (int)(((long long)len * g) / GSP);
    int i1 = b0 + (int)(((long long)len * (g + 1)) / GSP);
    for (int i = i0 + threadIdx.x; i < i1; i += blockDim.x) {
        float2 pa = payA[i];
        int sd = __float_as_int(pa.x);
        float ev = __expf(pa.y);
        atomicAdd(&lsum[sd & mask], ev);
        atomicAdd(&lnum[sd & mask], ev * H0[sd >> shift]);
    }
    __syncthreads();
    size_t po = (size_t)blockIdx.x << shift;
    for (int t = threadIdx.x; t < bw; t += blockDim.x) {
        pSum[po + t] = lsum[t];
        pNum[po + t] = lnum[t];
    }
}

__global__ void __launch_bounds__(256) k_finA(
    const float* __restrict__ pSum, const float* __restrict__ pNum,
    float* __restrict__ H1, int shift, int n)
{
    int d = blockIdx.x * blockDim.x + threadIdx.x;
    if (d >= n) return;
    int c = d >> shift, t = d & ((1 << shift) - 1);
    size_t b = ((size_t)c * GSP) << shift;
    int bw = 1 << shift;
    float s = 0.f, m = 0.f;
    #pragma unroll
    for (int g = 0; g < GSP; ++g) {
        s += pSum[b + (size_t)g * bw + t];
        m += pNum[b + (size_t)g * bw + t];
    }
    H1[d] = (s != 0.f) ? m / s : 0.f;
}

// passB main: edge MLP -> e2 (overwrites ef_s) + partial agg/s2
// 2 edges/thread + waves>=4/EU: VGPR<=128 (v4: 216 -> 2 waves/SIMD)
__global__ void __launch_bounds__(256, 4) k_passB(
    const float2* __restrict__ payA, float* __restrict__ ef_s,
    const float* __restrict__ H1,
    const float* __restrict__ W1, const float* __restrict__ B1,
    const float* __restrict__ W2, const float* __restrict__ B2,
    const int* __restrict__ base,
    float* __restrict__ pAgg, float* __restrict__ pS2, int shift, int n)
{
    __shared__ float4 wA[16], wB[16], wC[16], wD[16], wV[16];
    __shared__ float h1loc[256], lagg[256], ls2[256];
    int bw = 1 << shift, mask = bw - 1;
    int c = blockIdx.x / GSP, g = blockIdx.x % GSP;
    if (threadIdx.x < 16) {
        int j4 = threadIdx.x;
        const float4* W1v = reinterpret_cast<const float4*>(W1);
        wA[j4] = W1v[j4];
        wB[j4] = W1v[16 + j4];
        wC[j4] = W1v[32 + j4];
        wD[j4] = reinterpret_cast<const float4*>(B1)[j4];
        wV[j4] = reinterpret_cast<const float4*>(W2)[j4];
    }
    int d0 = c << shift;
    for (int t = threadIdx.x; t < bw; t += blockDim.x) {
        int d = d0 + t;
        h1loc[t] = (d < n) ? H1[d] : 0.f;
        lagg[t] = 0.f;
        ls2[t] = 0.f;
    }
    __syncthreads();
    const float b2 = B2[0];
    int b0 = base[c], len = base[c + 1] - b0;
    int i0 = b0 + (int)(((long long)len * g) / GSP);
    int i1 = b0 + (int)(((long long)len * (g + 1)) / GSP);
    const int T = blockDim.x;
    for (int i = i0 + (int)threadIdx.x; i < i1; i += 2 * T) {
        float x0[2], hs[2], hd[2], o[2];
        int lo[2], pos[2];
        bool val[2];
        #pragma unroll
        for (int u = 0; u < 2; ++u) {
            int j = i + u * T;
            val[u] = (j < i1);
            pos[u] = j;
            if (val[u]) {
                float2 pa = payA[j];
                int sd = __float_as_int(pa.x);
                lo[u] = sd & mask;
                x0[u] = ef_s[j];
                hs[u] = H1[sd >> shift];
                hd[u] = h1loc[lo[u]];
            } else { lo[u] = 0; x0[u] = 0.f; hs[u] = 0.f; hd[u] = 0.f; }
            o[u] = b2;
        }
        #pragma unroll
        for (int j4 = 0; j4 < 16; ++j4) {
            float4 a = wA[j4], b = wB[j4], cc = wC[j4], dd = wD[j4], v = wV[j4];
            #pragma unroll
            for (int u = 0; u < 2; ++u) {
                float t0 = fmaf(x0[u], a.x, fmaf(hs[u], b.x, fmaf(hd[u], cc.x, dd.x)));
                o[u] = fmaf(fmaxf(t0, 0.f), v.x, o[u]);
                float t1 = fmaf(x0[u], a.y, fmaf(hs[u], b.y, fmaf(hd[u], cc.y, dd.y)));
                o[u] = fmaf(fmaxf(t1, 0.f), v.y, o[u]);
                float t2 = fmaf(x0[u], a.z, fmaf(hs[u], b.z, fmaf(hd[u], cc.z, dd.z)));
                o[u] = fmaf(fmaxf(t2, 0.f), v.z, o[u]);
                float t3 = fmaf(x0[u], a.w, fmaf(hs[u], b.w, fmaf(hd[u], cc.w, dd.w)));
                o[u] = fmaf(fmaxf(t3, 0.f), v.w, o[u]);
            }
        }
        #pragma unroll
        for (int u = 0; u < 2; ++u) {
            if (val[u]) {
                float eh = fmaxf(o[u], 0.f);
                float ex = __expf(eh);
                ef_s[pos[u]] = ex;
                atomicAdd(&lagg[lo[u]], eh);
                atomicAdd(&ls2[lo[u]], ex);
            }
        }
    }
    __syncthreads();
    size_t po = (size_t)blockIdx.x << shift;
    for (int t = threadIdx.x; t < bw; t += blockDim.x) {
        pAgg[po + t] = lagg[t];
        pS2[po + t] = ls2[t];
    }
}

// finB: sum partials; H2 = nuMLP(agg, h1); S2
__global__ void __launch_bounds__(256) k_finB(
    const float* __restrict__ pAgg, const float* __restrict__ pS2,
    const float* __restrict__ H1,
    const float* __restrict__ NW1, const float* __restrict__ NB1,
    const float* __restrict__ NW2, const float* __restrict__ NB2,
    float* __restrict__ H2, float* __restrict__ S2, int shift, int n)
{
    int d = blockIdx.x * blockDim.x + threadIdx.x;
    if (d >= n) return;
    int c = d >> shift, t = d & ((1 << shift) - 1);
    size_t b = ((size_t)c * GSP) << shift;
    int bw = 1 << shift;
    float agg = 0.f, s2 = 0.f;
    #pragma unroll
    for (int g = 0; g < GSP; ++g) {
        agg += pAgg[b + (size_t)g * bw + t];
        s2  += pS2[b + (size_t)g * bw + t];
    }
    float xh = H1[d];
    float o = NB2[0];
    #pragma unroll
    for (int j = 0; j < 64; ++j) {
        float a = fmaf(agg, NW1[j], fmaf(xh, NW1[64 + j], NB1[j]));
        o = fmaf(fmaxf(a, 0.f), NW2[j], o);
    }
    H2[d] = fmaxf(o, 0.f);
    S2[d] = s2;
}

// passC main: partial num2
__global__ void __launch_bounds__(256, 4) k_passC(
    const float2* __restrict__ payA, const float* __restrict__ e2_s,
    const float* __restrict__ H2, const int* __restrict__ base,
    float* __restrict__ pNum, int shift)
{
    __shared__ float lnum[256];
    int c = blockIdx.x / GSP, g = blockIdx.x % GSP;
    int bw = 1 << shift, mask = bw - 1;
    for (int t = threadIdx.x; t < bw; t += blockDim.x) lnum[t] = 0.f;
    __syncthreads();
    int b0 = base[c], len = base[c + 1] - b0;
    int i0 = b0 + (int)(((long long)len * g) / GSP);
    int i1 = b0 + (int)(((long long)len * (g + 1)) / GSP);
    for (int i = i0 + threadIdx.x; i < i1; i += blockDim.x) {
        float2 pa = payA[i];
        int sd = __float_as_int(pa.x);
        atomicAdd(&lnum[sd & mask], e2_s[i] * H2[sd >> shift]);
    }
    __syncthreads();
    size_t po = (size_t)blockIdx.x << shift;
    for (int t = threadIdx.x; t < bw; t += blockDim.x)
        pNum[po + t] = lnum[t];
}

// finC: sum partials; OUT = decMLP(num2/s2)
__global__ void __launch_bounds__(256) k_finC(
    const float* __restrict__ pNum, const float* __restrict__ S2,
    const float* __restrict__ W1, const float* __restrict__ B1,
    const float* __restrict__ W2, const float* __restrict__ B2,
    float* __restrict__ OUT, int shift, int n)
{
    int d = blockIdx.x * blockDim.x + threadIdx.x;
    if (d >= n) return;
    int c = d >> shift, t = d & ((1 << shift) - 1);
    size_t b = ((size_t)c * GSP) << shift;
    int bw = 1 << shift;
    float m = 0.f;
    #pragma unroll
    for (int g = 0; g < GSP; ++g) m += pNum[b + (size_t)g * bw + t];
    float s = S2[d];
    float x = (s != 0.f) ? m / s : 0.f;
    float o = B2[0];
    #pragma unroll
    for (int j = 0; j < 64; ++j) {
        float a = fmaf(x, W1[j], B1[j]);
        o = fmaf(fmaxf(a, 0.f), W2[j], o);
    }
    OUT[d] = fmaxf(o, 0.f);
}

// ===================== fallback (atomic path) ==============================

__device__ __forceinline__ void atomAddF(float* p, float v) { unsafeAtomicAdd(p, v); }

__global__ void k_zero(float* __restrict__ p, int n) {
    int i = blockIdx.x * blockDim.x + threadIdx.x;
    if (i < n) p[i] = 0.f;
}

__global__ void __launch_bounds__(256) k_agg1(
    const float* __restrict__ DIST, const int* __restrict__ SRC,
    const int* __restrict__ DST, const float* __restrict__ H0,
    float* __restrict__ S1, float* __restrict__ NUM1, int e)
{
    int i = blockIdx.x * blockDim.x + threadIdx.x;
    if (i >= e) return;
    float ev = __expf(DIST[i]);
    atomAddF(&S1[DST[i]], ev);
    atomAddF(&NUM1[DST[i]], ev * H0[SRC[i]]);
}

__global__ void k_div(const float* __restrict__ NUM, const float* __restrict__ S,
                      float* __restrict__ H, int n) {
    int i = blockIdx.x * blockDim.x + threadIdx.x;
    if (i < n) {
        float s = S[i];
        H[i] = (s != 0.f) ? NUM[i] / s : 0.f;
    }
}

__global__ void __launch_bounds__(256) k_edgeF(
    const float* __restrict__ EF, const int* __restrict__ SRC,
    const int* __restrict__ DST, const float* __restrict__ H1,
    const float* __restrict__ W1, const float* __restrict__ B1,
    const float* __restrict__ W2, const float* __restrict__ B2,
    float* __restrict__ E2, float* __restrict__ AGG, float* __restrict__ S2, int e)
{
    int i = blockIdx.x * blockDim.x + threadIdx.x;
    if (i >= e) return;
    float x0 = EF[i];
    int s = SRC[i], d = DST[i];
    float h_s = H1[s], h_d = H1[d];
    float o = B2[0];
    for (int j = 0; j < 64; ++j) {
        float aj = fmaf(x0, W1[j], fmaf(h_s, W1[64+j], fmaf(h_d, W1[128+j], B1[j])));
        o = fmaf(fmaxf(aj, 0.f), W2[j], o);
    }
    float eh = fmaxf(o, 0.f);
    float ex = __expf(eh);
    E2[i] = ex;
    atomAddF(&AGG[d], eh);
    atomAddF(&S2[d], ex);
}

__global__ void k_nu(const float* __restrict__ AGG, const float* __restrict__ H1,
                     const float* __restrict__ W1, const float* __restrict__ B1,
                     const float* __restrict__ W2, const float* __restrict__ B2,
                     float* __restrict__ H2, int n)
{
    int i = blockIdx.x * blockDim.x + threadIdx.x;
    if (i >= n) return;
    float x0 = AGG[i], x1 = H1[i];
    float o = B2[0];
    #pragma unroll
    for (int j = 0; j < 64; ++j) {
        float a = fmaf(x0, W1[j], fmaf(x1, W1[64 + j], B1[j]));
        o = fmaf(fmaxf(a, 0.f), W2[j], o);
    }
    H2[i] = fmaxf(o, 0.f);
}

__global__ void __launch_bounds__(256) k_agg2F(
    const float* __restrict__ E2, const int* __restrict__ SRC,
    const int* __restrict__ DST, const float* __restrict__ H2,
    float* __restrict__ NUM2, int e)
{
    int i = blockIdx.x * blockDim.x + threadIdx.x;
    if (i >= e) return;
    atomAddF(&NUM2[DST[i]], E2[i] * H2[SRC[i]]);
}

__global__ void k_final(const float* __restrict__ NUM2, const float* __restrict__ S2,
                        const float* __restrict__ W1, const float* __restrict__ B1,
                        const float* __restrict__ W2, const float* __restrict__ B2,
                        float* __restrict__ OUT, int n)
{
    int i = blockIdx.x * blockDim.x + threadIdx.x;
    if (i >= n) return;
    float s = S2[i];
    float x = (s != 0.f) ? NUM2[i] / s : 0.f;
    float o = B2[0];
    #pragma unroll
    for (int j = 0; j < 64; ++j) {
        float a = fmaf(x, W1[j], B1[j]);
        o = fmaf(fmaxf(a, 0.f), W2[j], o);
    }
    OUT[i] = fmaxf(o, 0.f);
}

// ============================ launch =======================================

extern "C" void kernel_launch(void* const* d_in, const int* in_sizes, int n_in,
                              void* d_out, int out_size, void* d_ws, size_t ws_size,
                              hipStream_t stream)
{
    const float* node_feat = (const float*)d_in[0];
    const float* edge_feat = (const float*)d_in[1];
    const float* edge_dist = (const float*)d_in[2];
    const int*   src       = (const int*)d_in[3];
    const int*   dst       = (const int*)d_in[4];
    const float* enc_w1 = (const float*)d_in[5];
    const float* enc_b1 = (const float*)d_in[6];
    const float* enc_w2 = (const float*)d_in[7];
    const float* enc_b2 = (const float*)d_in[8];
    const float* nu_w1  = (const float*)d_in[9];
    const float* nu_b1  = (const float*)d_in[10];
    const float* nu_w2  = (const float*)d_in[11];
    const float* nu_b2  = (const float*)d_in[12];
    const float* eu_w1  = (const float*)d_in[13];
    const float* eu_b1  = (const float*)d_in[14];
    const float* eu_w2  = (const float*)d_in[15];
    const float* eu_b2  = (const float*)d_in[16];
    const float* dec_w1 = (const float*)d_in[17];
    const float* dec_b1 = (const float*)d_in[18];
    const float* dec_w2 = (const float*)d_in[19];
    const float* dec_b2 = (const float*)d_in[20];

    const int n = in_sizes[0] / 128;
    const int e = in_sizes[1];
    const int B = 256;

    int shift = 8;
    while ((((n + (1 << shift) - 1) >> shift) > 512) && shift < 10) shift++;
    const int nbkt = (n + (1 << shift) - 1) >> shift;
    int epb = (e + NHB - 1) / NHB;
    epb = (epb + 3) & ~3;

    // ws layout (4B words): h0,h1,h2,s2 [4n] | base[nbkt+1] bktCnt[nbkt]
    // hist[nbkt*NHB] | pad8 | payA[2e] | ef_s[e] | pP0[nbkt*G*bw] | pP1[...]
    float* ws = (float*)d_ws;
    size_t w = (size_t)4 * n;
    int* base   = (int*)(ws + w); w += nbkt + 1;
    int* bktCnt = (int*)(ws + w); w += nbkt;
    int* hist   = (int*)(ws + w); w += (size_t)nbkt * NHB;
    w = (w + 1) & ~(size_t)1;
    float2* payA = (float2*)(ws + w); w += (size_t)2 * e;
    float* ef_s  = ws + w; w += e;
    size_t psz = ((size_t)nbkt * GSP) << shift;
    float* pP0 = ws + w; w += psz;
    float* pP1 = ws + w; w += psz;
    size_t need = w * 4;

    float* h0 = ws;
    float* h1 = ws + (size_t)1 * n;
    float* h2 = ws + (size_t)2 * n;
    float* s2 = ws + (size_t)3 * n;

    if (ws_size >= need && nbkt <= 512 && (1 << shift) <= 256 &&
        ((size_t)n << shift) < (1u << 30)) {
        const int gE = nbkt * GSP;
        hipLaunchKernelGGL(k_chist, dim3(NHB), dim3(B), 0, stream,
                           dst, hist, e, nbkt, shift, epb);
        hipLaunchKernelGGL(k_scanA, dim3(nbkt), dim3(B), 0, stream, hist, bktCnt);
        hipLaunchKernelGGL(k_scanB, dim3(1), dim3(B), 0, stream, bktCnt, base, nbkt, e);
        hipLaunchKernelGGL(k_scatter, dim3(NHB), dim3(B), 0, stream,
                           dst, src, edge_dist, edge_feat, hist, base,
                           payA, ef_s, e, nbkt, shift, epb);
        hipLaunchKernelGGL(k_enc, dim3((n + B - 1) / B), dim3(B), 0, stream,
                           node_feat, enc_w1, enc_b1, enc_w2, enc_b2, h0, n);
        hipLaunchKernelGGL(k_passA, dim3(gE), dim3(B), 0, stream,
                           payA, h0, base, pP0, pP1, shift);
        hipLaunchKernelGGL(k_finA, dim3((n + B - 1) / B), dim3(B), 0, stream,
                           pP0, pP1, h1, shift, n);
        hipLaunchKernelGGL(k_passB, dim3(gE), dim3(B), 0, stream,
                           payA, ef_s, h1, eu_w1, eu_b1, eu_w2, eu_b2, base,
                           pP0, pP1, shift, n);
        hipLaunchKernelGGL(k_finB, dim3((n + B - 1) / B), dim3(B), 0, stream,
                           pP0, pP1, h1, nu_w1, nu_b1, nu_w2, nu_b2, h2, s2, shift, n);
        hipLaunchKernelGGL(k_passC, dim3(gE), dim3(B), 0, stream,
                           payA, ef_s /*e2*/, h2, base, pP0, shift);
        hipLaunchKernelGGL(k_finC, dim3((n + B - 1) / B), dim3(B), 0, stream,
                           pP0, s2, dec_w1, dec_b1, dec_w2, dec_b2,
                           (float*)d_out, shift, n);
    } else {
        // fallback: atomic path (needs 8n + e floats)
        float* agg  = ws + (size_t)2 * n;
        float* s1   = ws + (size_t)4 * n;
        float* num1 = ws + (size_t)5 * n;
        float* num2 = ws + (size_t)6 * n;
        float* h2f  = ws + (size_t)7 * n;
        float* e2   = ws + (size_t)8 * n;
        hipLaunchKernelGGL(k_zero, dim3((5 * n + B - 1) / B), dim3(B), 0, stream,
                           agg, 5 * n);
        hipLaunchKernelGGL(k_enc, dim3((n + B - 1) / B), dim3(B), 0, stream,
                           node_feat, enc_w1, enc_b1, enc_w2, enc_b2, h0, n);
        hipLaunchKernelGGL(k_agg1, dim3((e + B - 1) / B), dim3(B), 0, stream,
                           edge_dist, src, dst, h0, s1, num1, e);
        hipLaunchKernelGGL(k_div, dim3((n + B - 1) / B), dim3(B), 0, stream,
                           num1, s1, h1, n);
        hipLaunchKernelGGL(k_edgeF, dim3((e + B - 1) / B), dim3(B), 0, stream,
                           edge_feat, src, dst, h1, eu_w1, eu_b1, eu_w2, eu_b2,
                           e2, agg, s2, e);
        hipLaunchKernelGGL(k_nu, dim3((n + B - 1) / B), dim3(B), 0, stream,
                           agg, h1, nu_w1, nu_b1, nu_w2, nu_b2, h2f, n);
        hipLaunchKernelGGL(k_agg2F, dim3((e + B - 1) / B), dim3(B), 0, stream,
                           e2, src, dst, h2f, num2, e);
        hipLaunchKernelGGL(k_final, dim3((n + B - 1) / B), dim3(B), 0, stream,
                           num2, s2, dec_w1, dec_b1, dec_w2, dec_b2, (float*)d_out, n);
    }
}

// Round 6
// 402.835 us; speedup vs baseline: 4.7158x; 4.7158x over previous
//
#include <hip/hip_runtime.h>

// ---------------------------------------------------------------------------
// GraphElementNetwork forward, bucketed path v6:
//  - v4 structure (G-split LDS-private partials), but edge-MLP weights are
//    read as wave-uniform scalar loads (SGPR) with partial unroll, NOT staged
//    in LDS/VGPR arrays. v4's 216-VGPR allocation came from the compiler
//    hoisting all 80 weight floats into VGPRs; v5's launch_bounds(256,4)
//    forced spills (3.6 GB scratch FETCH). Structural fix: weights never
//    touch the vector RF.
// ---------------------------------------------------------------------------

#define NHB 256   // histogram / scatter blocks (1 per CU)
#define GSP 4     // slices per bucket in edge passes

// ============================ bucketing ====================================

__global__ void __launch_bounds__(256) k_chist(
    const int* __restrict__ DST, int* __restrict__ hist,
    int e, int nbkt, int shift, int epb)
{
    __shared__ int lh[512];
    for (int c = threadIdx.x; c < nbkt; c += blockDim.x) lh[c] = 0;
    __syncthreads();
    int b = blockIdx.x;
    int i0 = b * epb, i1 = min(i0 + epb, e);
    int nq = (i1 > i0) ? ((i1 - i0) >> 2) : 0;
    const int4* D4 = reinterpret_cast<const int4*>(DST + i0);
    for (int q = threadIdx.x; q < nq; q += blockDim.x) {
        int4 d = D4[q];
        atomicAdd(&lh[d.x >> shift], 1);
        atomicAdd(&lh[d.y >> shift], 1);
        atomicAdd(&lh[d.z >> shift], 1);
        atomicAdd(&lh[d.w >> shift], 1);
    }
    for (int i = i0 + 4 * nq + threadIdx.x; i < i1; i += blockDim.x)
        atomicAdd(&lh[DST[i] >> shift], 1);
    __syncthreads();
    for (int c = threadIdx.x; c < nbkt; c += blockDim.x)
        hist[(size_t)c * NHB + b] = lh[c];
}

__global__ void __launch_bounds__(256) k_scanA(
    int* __restrict__ hist, int* __restrict__ bktCnt)
{
    int c = blockIdx.x;
    int* row = hist + (size_t)c * NHB;
    __shared__ int part[256];
    int t = threadIdx.x;
    int v = row[t];
    part[t] = v;
    __syncthreads();
    for (int off = 1; off < 256; off <<= 1) {
        int x = 0;
        if (t >= off) x = part[t - off];
        __syncthreads();
        part[t] += x;
        __syncthreads();
    }
    if (t == 255) bktCnt[c] = part[255];
    row[t] = part[t] - v;
}

__global__ void __launch_bounds__(256) k_scanB(
    const int* __restrict__ bktCnt, int* __restrict__ base, int nbkt, int e)
{
    __shared__ int part[256];
    int t = threadIdx.x;
    int v[4];
    int sum = 0;
    #pragma unroll
    for (int u = 0; u < 4; ++u) {
        int idx = t * 4 + u;
        v[u] = (idx < nbkt) ? bktCnt[idx] : 0;
        sum += v[u];
    }
    part[t] = sum;
    __syncthreads();
    for (int off = 1; off < 256; off <<= 1) {
        int x = 0;
        if (t >= off) x = part[t - off];
        __syncthreads();
        part[t] += x;
        __syncthreads();
    }
    int run = (t == 0) ? 0 : part[t - 1];
    #pragma unroll
    for (int u = 0; u < 4; ++u) {
        int idx = t * 4 + u;
        if (idx < nbkt) base[idx] = run;
        run += v[u];
    }
    if (t == 0) base[nbkt] = e;
}

__global__ void __launch_bounds__(256) k_scatter(
    const int* __restrict__ DST, const int* __restrict__ SRC,
    const float* __restrict__ DIST, const float* __restrict__ EF,
    const int* __restrict__ hist, const int* __restrict__ base,
    float2* __restrict__ payA, float* __restrict__ ef_s,
    int e, int nbkt, int shift, int epb)
{
    __shared__ int loff[512];
    int b = blockIdx.x;
    for (int c = threadIdx.x; c < nbkt; c += blockDim.x)
        loff[c] = base[c] + hist[(size_t)c * NHB + b];
    __syncthreads();
    int i0 = b * epb, i1 = min(i0 + epb, e);
    if (i0 >= i1) return;
    int mask = (1 << shift) - 1;
    int nq = (i1 - i0) >> 2;
    const int4*   D4 = reinterpret_cast<const int4*>(DST + i0);
    const int4*   S4 = reinterpret_cast<const int4*>(SRC + i0);
    const float4* T4 = reinterpret_cast<const float4*>(DIST + i0);
    const float4* F4 = reinterpret_cast<const float4*>(EF + i0);
    for (int q = threadIdx.x; q < nq; q += blockDim.x) {
        int4 dv = D4[q];
        int4 sv = S4[q];
        float4 tv = T4[q];
        float4 fv = F4[q];
        #pragma unroll
        for (int u = 0; u < 4; ++u) {
            int d = (&dv.x)[u];
            int c = d >> shift;
            int pos = atomicAdd(&loff[c], 1);
            int sd = ((&sv.x)[u] << shift) | (d & mask);
            payA[pos] = make_float2(__int_as_float(sd), (&tv.x)[u]);
            ef_s[pos] = (&fv.x)[u];
        }
    }
    for (int i = i0 + 4 * nq + threadIdx.x; i < i1; i += blockDim.x) {
        int d = DST[i];
        int c = d >> shift;
        int pos = atomicAdd(&loff[c], 1);
        int sd = (SRC[i] << shift) | (d & mask);
        payA[pos] = make_float2(__int_as_float(sd), DIST[i]);
        ef_s[pos] = EF[i];
    }
}

// ============================ node encoder =================================

__global__ void __launch_bounds__(256) k_enc(
    const float* __restrict__ X, const float* __restrict__ W1,
    const float* __restrict__ B1, const float* __restrict__ W2,
    const float* __restrict__ B2, float* __restrict__ H0, int n)
{
    __shared__ float4 w1s[2048];
    for (int t = threadIdx.x; t < 2048; t += blockDim.x)
        w1s[t] = reinterpret_cast<const float4*>(W1)[t];
    __syncthreads();

    int i = blockIdx.x * blockDim.x + threadIdx.x;
    if (i >= n) return;

    const float4* xp = reinterpret_cast<const float4*>(X) + (size_t)i * 32;

    float acc[64];
    #pragma unroll
    for (int j = 0; j < 64; ++j) acc[j] = B1[j];

    for (int k4 = 0; k4 < 32; ++k4) {
        float4 xv = xp[k4];
        #pragma unroll
        for (int kk = 0; kk < 4; ++kk) {
            float x = (&xv.x)[kk];
            const float4* wrow = &w1s[(k4 * 4 + kk) * 16];
            #pragma unroll
            for (int j4 = 0; j4 < 16; ++j4) {
                float4 w = wrow[j4];
                acc[j4*4+0] = fmaf(x, w.x, acc[j4*4+0]);
                acc[j4*4+1] = fmaf(x, w.y, acc[j4*4+1]);
                acc[j4*4+2] = fmaf(x, w.z, acc[j4*4+2]);
                acc[j4*4+3] = fmaf(x, w.w, acc[j4*4+3]);
            }
        }
    }
    float o = B2[0];
    #pragma unroll
    for (int j = 0; j < 64; ++j)
        o = fmaf(fmaxf(acc[j], 0.f), W2[j], o);
    H0[i] = fmaxf(o, 0.f);
}

// ==================== bucketed edge passes (G-split) =======================
// partial layout: p[((c*GSP + g) << shift) + t]

__global__ void __launch_bounds__(256) k_passA(
    const float2* __restrict__ payA, const float* __restrict__ H0,
    const int* __restrict__ base,
    float* __restrict__ pSum, float* __restrict__ pNum, int shift)
{
    __shared__ float lsum[256], lnum[256];
    int c = blockIdx.x / GSP, g = blockIdx.x % GSP;
    int bw = 1 << shift, mask = bw - 1;
    for (int t = threadIdx.x; t < bw; t += blockDim.x) { lsum[t] = 0.f; lnum[t] = 0.f; }
    __syncthreads();
    int b0 = base[c], len = base[c + 1] - b0;
    int i0 = b0 + (int)(((long long)len * g) / GSP);
    int i1 = b0 + (int)(((long long)len * (g + 1)) / GSP);
    for (int i = i0 + threadIdx.x; i < i1; i += blockDim.x) {
        float2 pa = payA[i];
        int sd = __float_as_int(pa.x);
        float ev = __expf(pa.y);
        atomicAdd(&lsum[sd & mask], ev);
        atomicAdd(&lnum[sd & mask], ev * H0[sd >> shift]);
    }
    __syncthreads();
    size_t po = (size_t)blockIdx.x << shift;
    for (int t = threadIdx.x; t < bw; t += blockDim.x) {
        pSum[po + t] = lsum[t];
        pNum[po + t] = lnum[t];
    }
}

__global__ void __launch_bounds__(256) k_finA(
    const float* __restrict__ pSum, const float* __restrict__ pNum,
    float* __restrict__ H1, int shift, int n)
{
    int d = blockIdx.x * blockDim.x + threadIdx.x;
    if (d >= n) return;
    int c = d >> shift, t = d & ((1 << shift) - 1);
    size_t b = ((size_t)c * GSP) << shift;
    int bw = 1 << shift;
    float s = 0.f, m = 0.f;
    #pragma unroll
    for (int g = 0; g < GSP; ++g) {
        s += pSum[b + (size_t)g * bw + t];
        m += pNum[b + (size_t)g * bw + t];
    }
    H1[d] = (s != 0.f) ? m / s : 0.f;
}

// passB main: edge MLP -> e2 (overwrites ef_s) + partial agg/s2.
// Weights read as wave-uniform scalar (SGPR) loads inside #pragma unroll 4 —
// no LDS weight arrays, no VGPR hoisting (v4: 216 VGPR; v5: spills).
__global__ void __launch_bounds__(256) k_passB(
    const float2* __restrict__ payA, float* __restrict__ ef_s,
    const float* __restrict__ H1,
    const float* __restrict__ W1, const float* __restrict__ B1,
    const float* __restrict__ W2, const float* __restrict__ B2,
    const int* __restrict__ base,
    float* __restrict__ pAgg, float* __restrict__ pS2, int shift, int n)
{
    __shared__ float h1loc[256], lagg[256], ls2[256];
    int bw = 1 << shift, mask = bw - 1;
    int c = blockIdx.x / GSP, g = blockIdx.x % GSP;
    int d0 = c << shift;
    for (int t = threadIdx.x; t < bw; t += blockDim.x) {
        int d = d0 + t;
        h1loc[t] = (d < n) ? H1[d] : 0.f;
        lagg[t] = 0.f;
        ls2[t] = 0.f;
    }
    __syncthreads();
    const float b2 = B2[0];
    int b0 = base[c], len = base[c + 1] - b0;
    int i0 = b0 + (int)(((long long)len * g) / GSP);
    int i1 = b0 + (int)(((long long)len * (g + 1)) / GSP);
    const int T = blockDim.x;
    for (int i = i0 + (int)threadIdx.x; i < i1; i += 4 * T) {
        float x0[4], hs[4], hd[4], o[4];
        int lo[4], pos[4];
        bool val[4];
        #pragma unroll
        for (int u = 0; u < 4; ++u) {
            int j = i + u * T;
            val[u] = (j < i1);
            pos[u] = j;
            if (val[u]) {
                float2 pa = payA[j];
                int sd = __float_as_int(pa.x);
                lo[u] = sd & mask;
                x0[u] = ef_s[j];
                hs[u] = H1[sd >> shift];
                hd[u] = h1loc[lo[u]];
            } else { lo[u] = 0; x0[u] = 0.f; hs[u] = 0.f; hd[u] = 0.f; }
            o[u] = b2;
        }
        #pragma unroll 4
        for (int j = 0; j < 64; ++j) {
            float aj = W1[j], bj = W1[64 + j], cj = W1[128 + j];
            float dj = B1[j], vj = W2[j];
            #pragma unroll
            for (int u = 0; u < 4; ++u) {
                float t0 = fmaf(x0[u], aj, fmaf(hs[u], bj, fmaf(hd[u], cj, dj)));
                o[u] = fmaf(fmaxf(t0, 0.f), vj, o[u]);
            }
        }
        #pragma unroll
        for (int u = 0; u < 4; ++u) {
            if (val[u]) {
                float eh = fmaxf(o[u], 0.f);
                float ex = __expf(eh);
                ef_s[pos[u]] = ex;
                atomicAdd(&lagg[lo[u]], eh);
                atomicAdd(&ls2[lo[u]], ex);
            }
        }
    }
    __syncthreads();
    size_t po = (size_t)blockIdx.x << shift;
    for (int t = threadIdx.x; t < bw; t += blockDim.x) {
        pAgg[po + t] = lagg[t];
        pS2[po + t] = ls2[t];
    }
}

// finB: sum partials; H2 = nuMLP(agg, h1); S2
__global__ void __launch_bounds__(256) k_finB(
    const float* __restrict__ pAgg, const float* __restrict__ pS2,
    const float* __restrict__ H1,
    const float* __restrict__ NW1, const float* __restrict__ NB1,
    const float* __restrict__ NW2, const float* __restrict__ NB2,
    float* __restrict__ H2, float* __restrict__ S2, int shift, int n)
{
    int d = blockIdx.x * blockDim.x + threadIdx.x;
    if (d >= n) return;
    int c = d >> shift, t = d & ((1 << shift) - 1);
    size_t b = ((size_t)c * GSP) << shift;
    int bw = 1 << shift;
    float agg = 0.f, s2 = 0.f;
    #pragma unroll
    for (int g = 0; g < GSP; ++g) {
        agg += pAgg[b + (size_t)g * bw + t];
        s2  += pS2[b + (size_t)g * bw + t];
    }
    float xh = H1[d];
    float o = NB2[0];
    #pragma unroll 4
    for (int j = 0; j < 64; ++j) {
        float a = fmaf(agg, NW1[j], fmaf(xh, NW1[64 + j], NB1[j]));
        o = fmaf(fmaxf(a, 0.f), NW2[j], o);
    }
    H2[d] = fmaxf(o, 0.f);
    S2[d] = s2;
}

// passC main: partial num2
__global__ void __launch_bounds__(256) k_passC(
    const float2* __restrict__ payA, const float* __restrict__ e2_s,
    const float* __restrict__ H2, const int* __restrict__ base,
    float* __restrict__ pNum, int shift)
{
    __shared__ float lnum[256];
    int c = blockIdx.x / GSP, g = blockIdx.x % GSP;
    int bw = 1 << shift, mask = bw - 1;
    for (int t = threadIdx.x; t < bw; t += blockDim.x) lnum[t] = 0.f;
    __syncthreads();
    int b0 = base[c], len = base[c + 1] - b0;
    int i0 = b0 + (int)(((long long)len * g) / GSP);
    int i1 = b0 + (int)(((long long)len * (g + 1)) / GSP);
    for (int i = i0 + threadIdx.x; i < i1; i += blockDim.x) {
        float2 pa = payA[i];
        int sd = __float_as_int(pa.x);
        atomicAdd(&lnum[sd & mask], e2_s[i] * H2[sd >> shift]);
    }
    __syncthreads();
    size_t po = (size_t)blockIdx.x << shift;
    for (int t = threadIdx.x; t < bw; t += blockDim.x)
        pNum[po + t] = lnum[t];
}

// finC: sum partials; OUT = decMLP(num2/s2)
__global__ void __launch_bounds__(256) k_finC(
    const float* __restrict__ pNum, const float* __restrict__ S2,
    const float* __restrict__ W1, const float* __restrict__ B1,
    const float* __restrict__ W2, const float* __restrict__ B2,
    float* __restrict__ OUT, int shift, int n)
{
    int d = blockIdx.x * blockDim.x + threadIdx.x;
    if (d >= n) return;
    int c = d >> shift, t = d & ((1 << shift) - 1);
    size_t b = ((size_t)c * GSP) << shift;
    int bw = 1 << shift;
    float m = 0.f;
    #pragma unroll
    for (int g = 0; g < GSP; ++g) m += pNum[b + (size_t)g * bw + t];
    float s = S2[d];
    float x = (s != 0.f) ? m / s : 0.f;
    float o = B2[0];
    #pragma unroll 4
    for (int j = 0; j < 64; ++j) {
        float a = fmaf(x, W1[j], B1[j]);
        o = fmaf(fmaxf(a, 0.f), W2[j], o);
    }
    OUT[d] = fmaxf(o, 0.f);
}

// ===================== fallback (atomic path) ==============================

__device__ __forceinline__ void atomAddF(float* p, float v) { unsafeAtomicAdd(p, v); }

__global__ void k_zero(float* __restrict__ p, int n) {
    int i = blockIdx.x * blockDim.x + threadIdx.x;
    if (i < n) p[i] = 0.f;
}

__global__ void __launch_bounds__(256) k_agg1(
    const float* __restrict__ DIST, const int* __restrict__ SRC,
    const int* __restrict__ DST, const float* __restrict__ H0,
    float* __restrict__ S1, float* __restrict__ NUM1, int e)
{
    int i = blockIdx.x * blockDim.x + threadIdx.x;
    if (i >= e) return;
    float ev = __expf(DIST[i]);
    atomAddF(&S1[DST[i]], ev);
    atomAddF(&NUM1[DST[i]], ev * H0[SRC[i]]);
}

__global__ void k_div(const float* __restrict__ NUM, const float* __restrict__ S,
                      float* __restrict__ H, int n) {
    int i = blockIdx.x * blockDim.x + threadIdx.x;
    if (i < n) {
        float s = S[i];
        H[i] = (s != 0.f) ? NUM[i] / s : 0.f;
    }
}

__global__ void __launch_bounds__(256) k_edgeF(
    const float* __restrict__ EF, const int* __restrict__ SRC,
    const int* __restrict__ DST, const float* __restrict__ H1,
    const float* __restrict__ W1, const float* __restrict__ B1,
    const float* __restrict__ W2, const float* __restrict__ B2,
    float* __restrict__ E2, float* __restrict__ AGG, float* __restrict__ S2, int e)
{
    int i = blockIdx.x * blockDim.x + threadIdx.x;
    if (i >= e) return;
    float x0 = EF[i];
    int s = SRC[i], d = DST[i];
    float h_s = H1[s], h_d = H1[d];
    float o = B2[0];
    for (int j = 0; j < 64; ++j) {
        float aj = fmaf(x0, W1[j], fmaf(h_s, W1[64+j], fmaf(h_d, W1[128+j], B1[j])));
        o = fmaf(fmaxf(aj, 0.f), W2[j], o);
    }
    float eh = fmaxf(o, 0.f);
    float ex = __expf(eh);
    E2[i] = ex;
    atomAddF(&AGG[d], eh);
    atomAddF(&S2[d], ex);
}

__global__ void k_nu(const float* __restrict__ AGG, const float* __restrict__ H1,
                     const float* __restrict__ W1, const float* __restrict__ B1,
                     const float* __restrict__ W2, const float* __restrict__ B2,
                     float* __restrict__ H2, int n)
{
    int i = blockIdx.x * blockDim.x + threadIdx.x;
    if (i >= n) return;
    float x0 = AGG[i], x1 = H1[i];
    float o = B2[0];
    #pragma unroll
    for (int j = 0; j < 64; ++j) {
        float a = fmaf(x0, W1[j], fmaf(x1, W1[64 + j], B1[j]));
        o = fmaf(fmaxf(a, 0.f), W2[j], o);
    }
    H2[i] = fmaxf(o, 0.f);
}

__global__ void __launch_bounds__(256) k_agg2F(
    const float* __restrict__ E2, const int* __restrict__ SRC,
    const int* __restrict__ DST, const float* __restrict__ H2,
    float* __restrict__ NUM2, int e)
{
    int i = blockIdx.x * blockDim.x + threadIdx.x;
    if (i >= e) return;
    atomAddF(&NUM2[DST[i]], E2[i] * H2[SRC[i]]);
}

__global__ void k_final(const float* __restrict__ NUM2, const float* __restrict__ S2,
                        const float* __restrict__ W1, const float* __restrict__ B1,
                        const float* __restrict__ W2, const float* __restrict__ B2,
                        float* __restrict__ OUT, int n)
{
    int i = blockIdx.x * blockDim.x + threadIdx.x;
    if (i >= n) return;
    float s = S2[i];
    float x = (s != 0.f) ? NUM2[i] / s : 0.f;
    float o = B2[0];
    #pragma unroll
    for (int j = 0; j < 64; ++j) {
        float a = fmaf(x, W1[j], B1[j]);
        o = fmaf(fmaxf(a, 0.f), W2[j], o);
    }
    OUT[i] = fmaxf(o, 0.f);
}

// ============================ launch =======================================

extern "C" void kernel_launch(void* const* d_in, const int* in_sizes, int n_in,
                              void* d_out, int out_size, void* d_ws, size_t ws_size,
                              hipStream_t stream)
{
    const float* node_feat = (const float*)d_in[0];
    const float* edge_feat = (const float*)d_in[1];
    const float* edge_dist = (const float*)d_in[2];
    const int*   src       = (const int*)d_in[3];
    const int*   dst       = (const int*)d_in[4];
    const float* enc_w1 = (const float*)d_in[5];
    const float* enc_b1 = (const float*)d_in[6];
    const float* enc_w2 = (const float*)d_in[7];
    const float* enc_b2 = (const float*)d_in[8];
    const float* nu_w1  = (const float*)d_in[9];
    const float* nu_b1  = (const float*)d_in[10];
    const float* nu_w2  = (const float*)d_in[11];
    const float* nu_b2  = (const float*)d_in[12];
    const float* eu_w1  = (const float*)d_in[13];
    const float* eu_b1  = (const float*)d_in[14];
    const float* eu_w2  = (const float*)d_in[15];
    const float* eu_b2  = (const float*)d_in[16];
    const float* dec_w1 = (const float*)d_in[17];
    const float* dec_b1 = (const float*)d_in[18];
    const float* dec_w2 = (const float*)d_in[19];
    const float* dec_b2 = (const float*)d_in[20];

    const int n = in_sizes[0] / 128;
    const int e = in_sizes[1];
    const int B = 256;

    int shift = 8;
    while ((((n + (1 << shift) - 1) >> shift) > 512) && shift < 10) shift++;
    const int nbkt = (n + (1 << shift) - 1) >> shift;
    int epb = (e + NHB - 1) / NHB;
    epb = (epb + 3) & ~3;

    // ws layout (4B words): h0,h1,h2,s2 [4n] | base[nbkt+1] bktCnt[nbkt]
    // hist[nbkt*NHB] | pad8 | payA[2e] | ef_s[e] | pP0[nbkt*G*bw] | pP1[...]
    float* ws = (float*)d_ws;
    size_t w = (size_t)4 * n;
    int* base   = (int*)(ws + w); w += nbkt + 1;
    int* bktCnt = (int*)(ws + w); w += nbkt;
    int* hist   = (int*)(ws + w); w += (size_t)nbkt * NHB;
    w = (w + 1) & ~(size_t)1;
    float2* payA = (float2*)(ws + w); w += (size_t)2 * e;
    float* ef_s  = ws + w; w += e;
    size_t psz = ((size_t)nbkt * GSP) << shift;
    float* pP0 = ws + w; w += psz;
    float* pP1 = ws + w; w += psz;
    size_t need = w * 4;

    float* h0 = ws;
    float* h1 = ws + (size_t)1 * n;
    float* h2 = ws + (size_t)2 * n;
    float* s2 = ws + (size_t)3 * n;

    if (ws_size >= need && nbkt <= 512 && (1 << shift) <= 256 &&
        ((size_t)n << shift) < (1u << 30)) {
        const int gE = nbkt * GSP;
        hipLaunchKernelGGL(k_chist, dim3(NHB), dim3(B), 0, stream,
                           dst, hist, e, nbkt, shift, epb);
        hipLaunchKernelGGL(k_scanA, dim3(nbkt), dim3(B), 0, stream, hist, bktCnt);
        hipLaunchKernelGGL(k_scanB, dim3(1), dim3(B), 0, stream, bktCnt, base, nbkt, e);
        hipLaunchKernelGGL(k_scatter, dim3(NHB), dim3(B), 0, stream,
                           dst, src, edge_dist, edge_feat, hist, base,
                           payA, ef_s, e, nbkt, shift, epb);
        hipLaunchKernelGGL(k_enc, dim3((n + B - 1) / B), dim3(B), 0, stream,
                           node_feat, enc_w1, enc_b1, enc_w2, enc_b2, h0, n);
        hipLaunchKernelGGL(k_passA, dim3(gE), dim3(B), 0, stream,
                           payA, h0, base, pP0, pP1, shift);
        hipLaunchKernelGGL(k_finA, dim3((n + B - 1) / B), dim3(B), 0, stream,
                           pP0, pP1, h1, shift, n);
        hipLaunchKernelGGL(k_passB, dim3(gE), dim3(B), 0, stream,
                           payA, ef_s, h1, eu_w1, eu_b1, eu_w2, eu_b2, base,
                           pP0, pP1, shift, n);
        hipLaunchKernelGGL(k_finB, dim3((n + B - 1) / B), dim3(B), 0, stream,
                           pP0, pP1, h1, nu_w1, nu_b1, nu_w2, nu_b2, h2, s2, shift, n);
        hipLaunchKernelGGL(k_passC, dim3(gE), dim3(B), 0, stream,
                           payA, ef_s /*e2*/, h2, base, pP0, shift);
        hipLaunchKernelGGL(k_finC, dim3((n + B - 1) / B), dim3(B), 0, stream,
                           pP0, s2, dec_w1, dec_b1, dec_w2, dec_b2,
                           (float*)d_out, shift, n);
    } else {
        // fallback: atomic path (needs 8n + e floats)
        float* agg  = ws + (size_t)2 * n;
        float* s1   = ws + (size_t)4 * n;
        float* num1 = ws + (size_t)5 * n;
        float* num2 = ws + (size_t)6 * n;
        float* h2f  = ws + (size_t)7 * n;
        float* e2   = ws + (size_t)8 * n;
        hipLaunchKernelGGL(k_zero, dim3((5 * n + B - 1) / B), dim3(B), 0, stream,
                           agg, 5 * n);
        hipLaunchKernelGGL(k_enc, dim3((n + B - 1) / B), dim3(B), 0, stream,
                           node_feat, enc_w1, enc_b1, enc_w2, enc_b2, h0, n);
        hipLaunchKernelGGL(k_agg1, dim3((e + B - 1) / B), dim3(B), 0, stream,
                           edge_dist, src, dst, h0, s1, num1, e);
        hipLaunchKernelGGL(k_div, dim3((n + B - 1) / B), dim3(B), 0, stream,
                           num1, s1, h1, n);
        hipLaunchKernelGGL(k_edgeF, dim3((e + B - 1) / B), dim3(B), 0, stream,
                           edge_feat, src, dst, h1, eu_w1, eu_b1, eu_w2, eu_b2,
                           e2, agg, s2, e);
        hipLaunchKernelGGL(k_nu, dim3((n + B - 1) / B), dim3(B), 0, stream,
                           agg, h1, nu_w1, nu_b1, nu_w2, nu_b2, h2f, n);
        hipLaunchKernelGGL(k_agg2F, dim3((e + B - 1) / B), dim3(B), 0, stream,
                           e2, src, dst, h2f, num2, e);
        hipLaunchKernelGGL(k_final, dim3((n + B - 1) / B), dim3(B), 0, stream,
                           num2, s2, dec_w1, dec_b1, dec_w2, dec_b2, (float*)d_out, n);
    }
}

// Round 7
// 402.395 us; speedup vs baseline: 4.7210x; 1.0011x over previous
//
#include <hip/hip_runtime.h>

// ---------------------------------------------------------------------------
// GraphElementNetwork forward, bucketed path v7:
//  - shift=9 (bucket width 512, nbkt~196): halves scatter's open write-line
//    set (v6: 780 lines/block -> 4.4x write amplification, WRITE 335MB).
//  - nontemporal loads on all streaming reads (scatter inputs, pass payload)
//    so L2 keeps write-combining lines / gather arrays instead of streams.
//  - G (slices per bucket) is runtime, largest of {8,4,2,1} fitting ws_size.
//  - edge-MLP weights stay as wave-uniform scalar loads (v6 fix; v4=216 VGPR
//    hoist, v5=spill catastrophe).
// ---------------------------------------------------------------------------

#define NHB 256   // histogram / scatter blocks (1 per CU)

typedef int   iv4 __attribute__((ext_vector_type(4)));
typedef float fv4 __attribute__((ext_vector_type(4)));
typedef float fv2 __attribute__((ext_vector_type(2)));

// ============================ bucketing ====================================

__global__ void __launch_bounds__(256) k_chist(
    const int* __restrict__ DST, int* __restrict__ hist,
    int e, int nbkt, int shift, int epb)
{
    __shared__ int lh[512];
    for (int c = threadIdx.x; c < nbkt; c += blockDim.x) lh[c] = 0;
    __syncthreads();
    int b = blockIdx.x;
    int i0 = b * epb, i1 = min(i0 + epb, e);
    int nq = (i1 > i0) ? ((i1 - i0) >> 2) : 0;
    const iv4* D4 = reinterpret_cast<const iv4*>(DST + i0);
    for (int q = threadIdx.x; q < nq; q += blockDim.x) {
        iv4 d = D4[q];
        atomicAdd(&lh[d.x >> shift], 1);
        atomicAdd(&lh[d.y >> shift], 1);
        atomicAdd(&lh[d.z >> shift], 1);
        atomicAdd(&lh[d.w >> shift], 1);
    }
    for (int i = i0 + 4 * nq + threadIdx.x; i < i1; i += blockDim.x)
        atomicAdd(&lh[DST[i] >> shift], 1);
    __syncthreads();
    for (int c = threadIdx.x; c < nbkt; c += blockDim.x)
        hist[(size_t)c * NHB + b] = lh[c];
}

__global__ void __launch_bounds__(256) k_scanA(
    int* __restrict__ hist, int* __restrict__ bktCnt)
{
    int c = blockIdx.x;
    int* row = hist + (size_t)c * NHB;
    __shared__ int part[256];
    int t = threadIdx.x;
    int v = row[t];
    part[t] = v;
    __syncthreads();
    for (int off = 1; off < 256; off <<= 1) {
        int x = 0;
        if (t >= off) x = part[t - off];
        __syncthreads();
        part[t] += x;
        __syncthreads();
    }
    if (t == 255) bktCnt[c] = part[255];
    row[t] = part[t] - v;
}

__global__ void __launch_bounds__(256) k_scanB(
    const int* __restrict__ bktCnt, int* __restrict__ base, int nbkt, int e)
{
    __shared__ int part[256];
    int t = threadIdx.x;
    int v[4];
    int sum = 0;
    #pragma unroll
    for (int u = 0; u < 4; ++u) {
        int idx = t * 4 + u;
        v[u] = (idx < nbkt) ? bktCnt[idx] : 0;
        sum += v[u];
    }
    part[t] = sum;
    __syncthreads();
    for (int off = 1; off < 256; off <<= 1) {
        int x = 0;
        if (t >= off) x = part[t - off];
        __syncthreads();
        part[t] += x;
        __syncthreads();
    }
    int run = (t == 0) ? 0 : part[t - 1];
    #pragma unroll
    for (int u = 0; u < 4; ++u) {
        int idx = t * 4 + u;
        if (idx < nbkt) base[idx] = run;
        run += v[u];
    }
    if (t == 0) base[nbkt] = e;
}

__global__ void __launch_bounds__(256) k_scatter(
    const int* __restrict__ DST, const int* __restrict__ SRC,
    const float* __restrict__ DIST, const float* __restrict__ EF,
    const int* __restrict__ hist, const int* __restrict__ base,
    float2* __restrict__ payA, float* __restrict__ ef_s,
    int e, int nbkt, int shift, int epb)
{
    __shared__ int loff[512];
    int b = blockIdx.x;
    for (int c = threadIdx.x; c < nbkt; c += blockDim.x)
        loff[c] = base[c] + hist[(size_t)c * NHB + b];
    __syncthreads();
    int i0 = b * epb, i1 = min(i0 + epb, e);
    if (i0 >= i1) return;
    int mask = (1 << shift) - 1;
    int nq = (i1 - i0) >> 2;
    const iv4* D4 = reinterpret_cast<const iv4*>(DST + i0);
    const iv4* S4 = reinterpret_cast<const iv4*>(SRC + i0);
    const fv4* T4 = reinterpret_cast<const fv4*>(DIST + i0);
    const fv4* F4 = reinterpret_cast<const fv4*>(EF + i0);
    for (int q = threadIdx.x; q < nq; q += blockDim.x) {
        iv4 dv = __builtin_nontemporal_load(D4 + q);   // streams: evict-first,
        iv4 sv = __builtin_nontemporal_load(S4 + q);   // keep L2 for the
        fv4 tv = __builtin_nontemporal_load(T4 + q);   // write-combining lines
        fv4 fv = __builtin_nontemporal_load(F4 + q);
        #pragma unroll
        for (int u = 0; u < 4; ++u) {
            int d = dv[u];
            int c = d >> shift;
            int pos = atomicAdd(&loff[c], 1);
            int sd = (sv[u] << shift) | (d & mask);
            payA[pos] = make_float2(__int_as_float(sd), tv[u]);
            ef_s[pos] = fv[u];
        }
    }
    for (int i = i0 + 4 * nq + threadIdx.x; i < i1; i += blockDim.x) {
        int d = DST[i];
        int c = d >> shift;
        int pos = atomicAdd(&loff[c], 1);
        int sd = (SRC[i] << shift) | (d & mask);
        payA[pos] = make_float2(__int_as_float(sd), DIST[i]);
        ef_s[pos] = EF[i];
    }
}

// ============================ node encoder =================================

__global__ void __launch_bounds__(256) k_enc(
    const float* __restrict__ X, const float* __restrict__ W1,
    const float* __restrict__ B1, const float* __restrict__ W2,
    const float* __restrict__ B2, float* __restrict__ H0, int n)
{
    __shared__ float4 w1s[2048];
    for (int t = threadIdx.x; t < 2048; t += blockDim.x)
        w1s[t] = reinterpret_cast<const float4*>(W1)[t];
    __syncthreads();

    int i = blockIdx.x * blockDim.x + threadIdx.x;
    if (i >= n) return;

    const float4* xp = reinterpret_cast<const float4*>(X) + (size_t)i * 32;

    float acc[64];
    #pragma unroll
    for (int j = 0; j < 64; ++j) acc[j] = B1[j];

    for (int k4 = 0; k4 < 32; ++k4) {
        float4 xv = xp[k4];
        #pragma unroll
        for (int kk = 0; kk < 4; ++kk) {
            float x = (&xv.x)[kk];
            const float4* wrow = &w1s[(k4 * 4 + kk) * 16];
            #pragma unroll
            for (int j4 = 0; j4 < 16; ++j4) {
                float4 w = wrow[j4];
                acc[j4*4+0] = fmaf(x, w.x, acc[j4*4+0]);
                acc[j4*4+1] = fmaf(x, w.y, acc[j4*4+1]);
                acc[j4*4+2] = fmaf(x, w.z, acc[j4*4+2]);
                acc[j4*4+3] = fmaf(x, w.w, acc[j4*4+3]);
            }
        }
    }
    float o = B2[0];
    #pragma unroll
    for (int j = 0; j < 64; ++j)
        o = fmaf(fmaxf(acc[j], 0.f), W2[j], o);
    H0[i] = fmaxf(o, 0.f);
}

// ==================== bucketed edge passes (G-split) =======================
// partial layout: p[((c*G + g) << shift) + t]

__global__ void __launch_bounds__(256) k_passA(
    const float2* __restrict__ payA, const float* __restrict__ H0,
    const int* __restrict__ base,
    float* __restrict__ pSum, float* __restrict__ pNum, int shift, int G)
{
    __shared__ float lsum[512], lnum[512];
    int c = blockIdx.x / G, g = blockIdx.x % G;
    int bw = 1 << shift, mask = bw - 1;
    for (int t = threadIdx.x; t < bw; t += blockDim.x) { lsum[t] = 0.f; lnum[t] = 0.f; }
    __syncthreads();
    int b0 = base[c], len = base[c + 1] - b0;
    int i0 = b0 + (int)(((long long)len * g) / G);
    int i1 = b0 + (int)(((long long)len * (g + 1)) / G);
    for (int i = i0 + threadIdx.x; i < i1; i += blockDim.x) {
        fv2 pa = __builtin_nontemporal_load(
            reinterpret_cast<const fv2*>(payA) + i);
        int sd = __float_as_int(pa.x);
        float ev = __expf(pa.y);
        atomicAdd(&lsum[sd & mask], ev);
        atomicAdd(&lnum[sd & mask], ev * H0[sd >> shift]);
    }
    __syncthreads();
    size_t po = (size_t)blockIdx.x << shift;
    for (int t = threadIdx.x; t < bw; t += blockDim.x) {
        pSum[po + t] = lsum[t];
        pNum[po + t] = lnum[t];
    }
}

__global__ void __launch_bounds__(256) k_finA(
    const float* __restrict__ pSum, const float* __restrict__ pNum,
    float* __restrict__ H1, int shift, int n, int G)
{
    int d = blockIdx.x * blockDim.x + threadIdx.x;
    if (d >= n) return;
    int c = d >> shift, t = d & ((1 << shift) - 1);
    size_t b = (size_t)c * G << shift;
    int bw = 1 << shift;
    float s = 0.f, m = 0.f;
    for (int g = 0; g < G; ++g) {
        s += pSum[b + (size_t)g * bw + t];
        m += pNum[b + (size_t)g * bw + t];
    }
    H1[d] = (s != 0.f) ? m / s : 0.f;
}

// passB main: edge MLP -> e2 (overwrites ef_s) + partial agg/s2.
// Weights as wave-uniform scalar (SGPR) loads in #pragma unroll 4.
__global__ void __launch_bounds__(256) k_passB(
    const float2* __restrict__ payA, float* __restrict__ ef_s,
    const float* __restrict__ H1,
    const float* __restrict__ W1, const float* __restrict__ B1,
    const float* __restrict__ W2, const float* __restrict__ B2,
    const int* __restrict__ base,
    float* __restrict__ pAgg, float* __restrict__ pS2, int shift, int n, int G)
{
    __shared__ float h1loc[512], lagg[512], ls2[512];
    int bw = 1 << shift, mask = bw - 1;
    int c = blockIdx.x / G, g = blockIdx.x % G;
    int d0 = c << shift;
    for (int t = threadIdx.x; t < bw; t += blockDim.x) {
        int d = d0 + t;
        h1loc[t] = (d < n) ? H1[d] : 0.f;
        lagg[t] = 0.f;
        ls2[t] = 0.f;
    }
    __syncthreads();
    const float b2 = B2[0];
    int b0 = base[c], len = base[c + 1] - b0;
    int i0 = b0 + (int)(((long long)len * g) / G);
    int i1 = b0 + (int)(((long long)len * (g + 1)) / G);
    const int T = blockDim.x;
    for (int i = i0 + (int)threadIdx.x; i < i1; i += 4 * T) {
        float x0[4], hs[4], hd[4], o[4];
        int lo[4], pos[4];
        bool val[4];
        #pragma unroll
        for (int u = 0; u < 4; ++u) {
            int j = i + u * T;
            val[u] = (j < i1);
            pos[u] = j;
            if (val[u]) {
                fv2 pa = __builtin_nontemporal_load(
                    reinterpret_cast<const fv2*>(payA) + j);
                int sd = __float_as_int(pa.x);
                lo[u] = sd & mask;
                x0[u] = __builtin_nontemporal_load(ef_s + j);
                hs[u] = H1[sd >> shift];
                hd[u] = h1loc[lo[u]];
            } else { lo[u] = 0; x0[u] = 0.f; hs[u] = 0.f; hd[u] = 0.f; }
            o[u] = b2;
        }
        #pragma unroll 4
        for (int j = 0; j < 64; ++j) {
            float aj = W1[j], bj = W1[64 + j], cj = W1[128 + j];
            float dj = B1[j], vj = W2[j];
            #pragma unroll
            for (int u = 0; u < 4; ++u) {
                float t0 = fmaf(x0[u], aj, fmaf(hs[u], bj, fmaf(hd[u], cj, dj)));
                o[u] = fmaf(fmaxf(t0, 0.f), vj, o[u]);
            }
        }
        #pragma unroll
        for (int u = 0; u < 4; ++u) {
            if (val[u]) {
                float eh = fmaxf(o[u], 0.f);
                float ex = __expf(eh);
                ef_s[pos[u]] = ex;
                atomicAdd(&lagg[lo[u]], eh);
                atomicAdd(&ls2[lo[u]], ex);
            }
        }
    }
    __syncthreads();
    size_t po = (size_t)blockIdx.x << shift;
    for (int t = threadIdx.x; t < bw; t += blockDim.x) {
        pAgg[po + t] = lagg[t];
        pS2[po + t] = ls2[t];
    }
}

// finB: sum partials; H2 = nuMLP(agg, h1); S2
__global__ void __launch_bounds__(256) k_finB(
    const float* __restrict__ pAgg, const float* __restrict__ pS2,
    const float* __restrict__ H1,
    const float* __restrict__ NW1, const float* __restrict__ NB1,
    const float* __restrict__ NW2, const float* __restrict__ NB2,
    float* __restrict__ H2, float* __restrict__ S2, int shift, int n, int G)
{
    int d = blockIdx.x * blockDim.x + threadIdx.x;
    if (d >= n) return;
    int c = d >> shift, t = d & ((1 << shift) - 1);
    size_t b = (size_t)c * G << shift;
    int bw = 1 << shift;
    float agg = 0.f, s2 = 0.f;
    for (int g = 0; g < G; ++g) {
        agg += pAgg[b + (size_t)g * bw + t];
        s2  += pS2[b + (size_t)g * bw + t];
    }
    float xh = H1[d];
    float o = NB2[0];
    #pragma unroll 4
    for (int j = 0; j < 64; ++j) {
        float a = fmaf(agg, NW1[j], fmaf(xh, NW1[64 + j], NB1[j]));
        o = fmaf(fmaxf(a, 0.f), NW2[j], o);
    }
    H2[d] = fmaxf(o, 0.f);
    S2[d] = s2;
}

// passC main: partial num2
__global__ void __launch_bounds__(256) k_passC(
    const float2* __restrict__ payA, const float* __restrict__ e2_s,
    const float* __restrict__ H2, const int* __restrict__ base,
    float* __restrict__ pNum, int shift, int G)
{
    __shared__ float lnum[512];
    int c = blockIdx.x / G, g = blockIdx.x % G;
    int bw = 1 << shift, mask = bw - 1;
    for (int t = threadIdx.x; t < bw; t += blockDim.x) lnum[t] = 0.f;
    __syncthreads();
    int b0 = base[c], len = base[c + 1] - b0;
    int i0 = b0 + (int)(((long long)len * g) / G);
    int i1 = b0 + (int)(((long long)len * (g + 1)) / G);
    for (int i = i0 + threadIdx.x; i < i1; i += blockDim.x) {
        fv2 pa = __builtin_nontemporal_load(
            reinterpret_cast<const fv2*>(payA) + i);
        int sd = __float_as_int(pa.x);
        float e2 = __builtin_nontemporal_load(e2_s + i);
        atomicAdd(&lnum[sd & mask], e2 * H2[sd >> shift]);
    }
    __syncthreads();
    size_t po = (size_t)blockIdx.x << shift;
    for (int t = threadIdx.x; t < bw; t += blockDim.x)
        pNum[po + t] = lnum[t];
}

// finC: sum partials; OUT = decMLP(num2/s2)
__global__ void __launch_bounds__(256) k_finC(
    const float* __restrict__ pNum, const float* __restrict__ S2,
    const float* __restrict__ W1, const float* __restrict__ B1,
    const float* __restrict__ W2, const float* __restrict__ B2,
    float* __restrict__ OUT, int shift, int n, int G)
{
    int d = blockIdx.x * blockDim.x + threadIdx.x;
    if (d >= n) return;
    int c = d >> shift, t = d & ((1 << shift) - 1);
    size_t b = (size_t)c * G << shift;
    int bw = 1 << shift;
    float m = 0.f;
    for (int g = 0; g < G; ++g) m += pNum[b + (size_t)g * bw + t];
    float s = S2[d];
    float x = (s != 0.f) ? m / s : 0.f;
    float o = B2[0];
    #pragma unroll 4
    for (int j = 0; j < 64; ++j) {
        float a = fmaf(x, W1[j], B1[j]);
        o = fmaf(fmaxf(a, 0.f), W2[j], o);
    }
    OUT[d] = fmaxf(o, 0.f);
}

// ===================== fallback (atomic path) ==============================

__device__ __forceinline__ void atomAddF(float* p, float v) { unsafeAtomicAdd(p, v); }

__global__ void k_zero(float* __restrict__ p, int n) {
    int i = blockIdx.x * blockDim.x + threadIdx.x;
    if (i < n) p[i] = 0.f;
}

__global__ void __launch_bounds__(256) k_agg1(
    const float* __restrict__ DIST, const int* __restrict__ SRC,
    const int* __restrict__ DST, const float* __restrict__ H0,
    float* __restrict__ S1, float* __restrict__ NUM1, int e)
{
    int i = blockIdx.x * blockDim.x + threadIdx.x;
    if (i >= e) return;
    float ev = __expf(DIST[i]);
    atomAddF(&S1[DST[i]], ev);
    atomAddF(&NUM1[DST[i]], ev * H0[SRC[i]]);
}

__global__ void k_div(const float* __restrict__ NUM, const float* __restrict__ S,
                      float* __restrict__ H, int n) {
    int i = blockIdx.x * blockDim.x + threadIdx.x;
    if (i < n) {
        float s = S[i];
        H[i] = (s != 0.f) ? NUM[i] / s : 0.f;
    }
}

__global__ void __launch_bounds__(256) k_edgeF(
    const float* __restrict__ EF, const int* __restrict__ SRC,
    const int* __restrict__ DST, const float* __restrict__ H1,
    const float* __restrict__ W1, const float* __restrict__ B1,
    const float* __restrict__ W2, const float* __restrict__ B2,
    float* __restrict__ E2, float* __restrict__ AGG, float* __restrict__ S2, int e)
{
    int i = blockIdx.x * blockDim.x + threadIdx.x;
    if (i >= e) return;
    float x0 = EF[i];
    int s = SRC[i], d = DST[i];
    float h_s = H1[s], h_d = H1[d];
    float o = B2[0];
    for (int j = 0; j < 64; ++j) {
        float aj = fmaf(x0, W1[j], fmaf(h_s, W1[64+j], fmaf(h_d, W1[128+j], B1[j])));
        o = fmaf(fmaxf(aj, 0.f), W2[j], o);
    }
    float eh = fmaxf(o, 0.f);
    float ex = __expf(eh);
    E2[i] = ex;
    atomAddF(&AGG[d], eh);
    atomAddF(&S2[d], ex);
}

__global__ void k_nu(const float* __restrict__ AGG, const float* __restrict__ H1,
                     const float* __restrict__ W1, const float* __restrict__ B1,
                     const float* __restrict__ W2, const float* __restrict__ B2,
                     float* __restrict__ H2, int n)
{
    int i = blockIdx.x * blockDim.x + threadIdx.x;
    if (i >= n) return;
    float x0 = AGG[i], x1 = H1[i];
    float o = B2[0];
    #pragma unroll
    for (int j = 0; j < 64; ++j) {
        float a = fmaf(x0, W1[j], fmaf(x1, W1[64 + j], B1[j]));
        o = fmaf(fmaxf(a, 0.f), W2[j], o);
    }
    H2[i] = fmaxf(o, 0.f);
}

__global__ void __launch_bounds__(256) k_agg2F(
    const float* __restrict__ E2, const int* __restrict__ SRC,
    const int* __restrict__ DST, const float* __restrict__ H2,
    float* __restrict__ NUM2, int e)
{
    int i = blockIdx.x * blockDim.x + threadIdx.x;
    if (i >= e) return;
    atomAddF(&NUM2[DST[i]], E2[i] * H2[SRC[i]]);
}

__global__ void k_final(const float* __restrict__ NUM2, const float* __restrict__ S2,
                        const float* __restrict__ W1, const float* __restrict__ B1,
                        const float* __restrict__ W2, const float* __restrict__ B2,
                        float* __restrict__ OUT, int n)
{
    int i = blockIdx.x * blockDim.x + threadIdx.x;
    if (i >= n) return;
    float s = S2[i];
    float x = (s != 0.f) ? NUM2[i] / s : 0.f;
    float o = B2[0];
    #pragma unroll
    for (int j = 0; j < 64; ++j) {
        float a = fmaf(x, W1[j], B1[j]);
        o = fmaf(fmaxf(a, 0.f), W2[j], o);
    }
    OUT[i] = fmaxf(o, 0.f);
}

// ============================ launch =======================================

extern "C" void kernel_launch(void* const* d_in, const int* in_sizes, int n_in,
                              void* d_out, int out_size, void* d_ws, size_t ws_size,
                              hipStream_t stream)
{
    const float* node_feat = (const float*)d_in[0];
    const float* edge_feat = (const float*)d_in[1];
    const float* edge_dist = (const float*)d_in[2];
    const int*   src       = (const int*)d_in[3];
    const int*   dst       = (const int*)d_in[4];
    const float* enc_w1 = (const float*)d_in[5];
    const float* enc_b1 = (const float*)d_in[6];
    const float* enc_w2 = (const float*)d_in[7];
    const float* enc_b2 = (const float*)d_in[8];
    const float* nu_w1  = (const float*)d_in[9];
    const float* nu_b1  = (const float*)d_in[10];
    const float* nu_w2  = (const float*)d_in[11];
    const float* nu_b2  = (const float*)d_in[12];
    const float* eu_w1  = (const float*)d_in[13];
    const float* eu_b1  = (const float*)d_in[14];
    const float* eu_w2  = (const float*)d_in[15];
    const float* eu_b2  = (const float*)d_in[16];
    const float* dec_w1 = (const float*)d_in[17];
    const float* dec_b1 = (const float*)d_in[18];
    const float* dec_w2 = (const float*)d_in[19];
    const float* dec_b2 = (const float*)d_in[20];

    const int n = in_sizes[0] / 128;
    const int e = in_sizes[1];
    const int B = 256;

    // bucket width 512 (shift=9): ~196 buckets for n=100k -> ~392 open
    // write lines per scatter block (50KB), 1.6MB/XCD.
    int shift = 9;
    while ((((n + (1 << shift) - 1) >> shift) > 512) && shift < 12) shift++;
    const int nbkt = (n + (1 << shift) - 1) >> shift;
    int epb = (e + NHB - 1) / NHB;
    epb = (epb + 3) & ~3;

    // ws layout (4B words): h0,h1,h2,s2 [4n] | base[nbkt+1] bktCnt[nbkt]
    // hist[nbkt*NHB] | pad8 | payA[2e] | ef_s[e] | pP0[nbkt*G<<shift] | pP1
    float* ws = (float*)d_ws;
    size_t w = (size_t)4 * n;
    int* base   = (int*)(ws + w); w += nbkt + 1;
    int* bktCnt = (int*)(ws + w); w += nbkt;
    int* hist   = (int*)(ws + w); w += (size_t)nbkt * NHB;
    w = (w + 1) & ~(size_t)1;
    float2* payA = (float2*)(ws + w); w += (size_t)2 * e;
    float* ef_s  = ws + w; w += e;

    // pick largest G in {8,4,2,1} whose partial arrays fit the workspace
    int G = 8;
    size_t psz;
    size_t need;
    for (;;) {
        psz = ((size_t)nbkt * G) << shift;
        need = (w + 2 * psz) * 4;
        if (need <= ws_size || G == 1) break;
        G >>= 1;
    }
    float* pP0 = ws + w;
    float* pP1 = ws + w + psz;

    float* h0 = ws;
    float* h1 = ws + (size_t)1 * n;
    float* h2 = ws + (size_t)2 * n;
    float* s2 = ws + (size_t)3 * n;

    if (ws_size >= need && nbkt <= 512 && (1 << shift) <= 512 &&
        ((size_t)n << shift) < (1u << 30)) {
        const int gE = nbkt * G;
        hipLaunchKernelGGL(k_chist, dim3(NHB), dim3(B), 0, stream,
                           dst, hist, e, nbkt, shift, epb);
        hipLaunchKernelGGL(k_scanA, dim3(nbkt), dim3(B), 0, stream, hist, bktCnt);
        hipLaunchKernelGGL(k_scanB, dim3(1), dim3(B), 0, stream, bktCnt, base, nbkt, e);
        hipLaunchKernelGGL(k_scatter, dim3(NHB), dim3(B), 0, stream,
                           dst, src, edge_dist, edge_feat, hist, base,
                           payA, ef_s, e, nbkt, shift, epb);
        hipLaunchKernelGGL(k_enc, dim3((n + B - 1) / B), dim3(B), 0, stream,
                           node_feat, enc_w1, enc_b1, enc_w2, enc_b2, h0, n);
        hipLaunchKernelGGL(k_passA, dim3(gE), dim3(B), 0, stream,
                           payA, h0, base, pP0, pP1, shift, G);
        hipLaunchKernelGGL(k_finA, dim3((n + B - 1) / B), dim3(B), 0, stream,
                           pP0, pP1, h1, shift, n, G);
        hipLaunchKernelGGL(k_passB, dim3(gE), dim3(B), 0, stream,
                           payA, ef_s, h1, eu_w1, eu_b1, eu_w2, eu_b2, base,
                           pP0, pP1, shift, n, G);
        hipLaunchKernelGGL(k_finB, dim3((n + B - 1) / B), dim3(B), 0, stream,
                           pP0, pP1, h1, nu_w1, nu_b1, nu_w2, nu_b2, h2, s2,
                           shift, n, G);
        hipLaunchKernelGGL(k_passC, dim3(gE), dim3(B), 0, stream,
                           payA, ef_s /*e2*/, h2, base, pP0, shift, G);
        hipLaunchKernelGGL(k_finC, dim3((n + B - 1) / B), dim3(B), 0, stream,
                           pP0, s2, dec_w1, dec_b1, dec_w2, dec_b2,
                           (float*)d_out, shift, n, G);
    } else {
        // fallback: atomic path (needs 8n + e floats)
        float* agg  = ws + (size_t)2 * n;
        float* s1   = ws + (size_t)4 * n;
        float* num1 = ws + (size_t)5 * n;
        float* num2 = ws + (size_t)6 * n;
        float* h2f  = ws + (size_t)7 * n;
        float* e2   = ws + (size_t)8 * n;
        hipLaunchKernelGGL(k_zero, dim3((5 * n + B - 1) / B), dim3(B), 0, stream,
                           agg, 5 * n);
        hipLaunchKernelGGL(k_enc, dim3((n + B - 1) / B), dim3(B), 0, stream,
                           node_feat, enc_w1, enc_b1, enc_w2, enc_b2, h0, n);
        hipLaunchKernelGGL(k_agg1, dim3((e + B - 1) / B), dim3(B), 0, stream,
                           edge_dist, src, dst, h0, s1, num1, e);
        hipLaunchKernelGGL(k_div, dim3((n + B - 1) / B), dim3(B), 0, stream,
                           num1, s1, h1, n);
        hipLaunchKernelGGL(k_edgeF, dim3((e + B - 1) / B), dim3(B), 0, stream,
                           edge_feat, src, dst, h1, eu_w1, eu_b1, eu_w2, eu_b2,
                           e2, agg, s2, e);
        hipLaunchKernelGGL(k_nu, dim3((n + B - 1) / B), dim3(B), 0, stream,
                           agg, h1, nu_w1, nu_b1, nu_w2, nu_b2, h2f, n);
        hipLaunchKernelGGL(k_agg2F, dim3((e + B - 1) / B), dim3(B), 0, stream,
                           e2, src, dst, h2f, num2, e);
        hipLaunchKernelGGL(k_final, dim3((n + B - 1) / B), dim3(B), 0, stream,
                           num2, s2, dec_w1, dec_b1, dec_w2, dec_b2, (float*)d_out, n);
    }
}

// Round 9
// 397.488 us; speedup vs baseline: 4.7793x; 1.0123x over previous
//
#include <hip/hip_runtime.h>

// ---------------------------------------------------------------------------
// GraphElementNetwork forward, bucketed path v8.1 (v8 + macro-arg build fix):
//  - passB edge-MLP packed as 2xfp32 (v_pk_fma_f32/v_pk_max_f32 via
//    __builtin_elementwise_*, feature-guarded) -> halves MLP VALU issue.
//  - passB software-pipelined: next chunk's payload loads issued BEFORE the
//    e2 store/atomic phase (compiler couldn't hoist across the in-place
//    ef_s overwrite; v7 VALUBusy stuck at 51%).
//  - passA/passC: 2-edge ILP.
//  - shift=9 buckets, G slices/bucket auto in {16,8,4,2,1} by ws_size.
//  - weights stay wave-uniform scalar loads (v6 lesson: never force them
//    into VGPRs (v4: 216 VGPR) or clamp regs (v5: spill catastrophe)).
// ---------------------------------------------------------------------------

#define NHB 256   // histogram / scatter blocks (1 per CU)

typedef int   iv4 __attribute__((ext_vector_type(4)));
typedef float fv4 __attribute__((ext_vector_type(4)));
typedef float fv2 __attribute__((ext_vector_type(2)));

#if __has_builtin(__builtin_elementwise_fma)
#define FMA2(a, b, c) __builtin_elementwise_fma((a), (b), (c))
#else
static __device__ __forceinline__ fv2 FMA2(fv2 a, fv2 b, fv2 c) {
    fv2 r; r.x = fmaf(a.x, b.x, c.x); r.y = fmaf(a.y, b.y, c.y); return r;
}
#endif
#if __has_builtin(__builtin_elementwise_max)
#define MAX2(a, b) __builtin_elementwise_max((a), (b))
#else
static __device__ __forceinline__ fv2 MAX2(fv2 a, fv2 b) {
    fv2 r; r.x = fmaxf(a.x, b.x); r.y = fmaxf(a.y, b.y); return r;
}
#endif

// ============================ bucketing ====================================

__global__ void __launch_bounds__(256) k_chist(
    const int* __restrict__ DST, int* __restrict__ hist,
    int e, int nbkt, int shift, int epb)
{
    __shared__ int lh[512];
    for (int c = threadIdx.x; c < nbkt; c += blockDim.x) lh[c] = 0;
    __syncthreads();
    int b = blockIdx.x;
    int i0 = b * epb, i1 = min(i0 + epb, e);
    int nq = (i1 > i0) ? ((i1 - i0) >> 2) : 0;
    const iv4* D4 = reinterpret_cast<const iv4*>(DST + i0);
    for (int q = threadIdx.x; q < nq; q += blockDim.x) {
        iv4 d = D4[q];
        atomicAdd(&lh[d.x >> shift], 1);
        atomicAdd(&lh[d.y >> shift], 1);
        atomicAdd(&lh[d.z >> shift], 1);
        atomicAdd(&lh[d.w >> shift], 1);
    }
    for (int i = i0 + 4 * nq + threadIdx.x; i < i1; i += blockDim.x)
        atomicAdd(&lh[DST[i] >> shift], 1);
    __syncthreads();
    for (int c = threadIdx.x; c < nbkt; c += blockDim.x)
        hist[(size_t)c * NHB + b] = lh[c];
}

__global__ void __launch_bounds__(256) k_scanA(
    int* __restrict__ hist, int* __restrict__ bktCnt)
{
    int c = blockIdx.x;
    int* row = hist + (size_t)c * NHB;
    __shared__ int part[256];
    int t = threadIdx.x;
    int v = row[t];
    part[t] = v;
    __syncthreads();
    for (int off = 1; off < 256; off <<= 1) {
        int x = 0;
        if (t >= off) x = part[t - off];
        __syncthreads();
        part[t] += x;
        __syncthreads();
    }
    if (t == 255) bktCnt[c] = part[255];
    row[t] = part[t] - v;
}

__global__ void __launch_bounds__(256) k_scanB(
    const int* __restrict__ bktCnt, int* __restrict__ base, int nbkt, int e)
{
    __shared__ int part[256];
    int t = threadIdx.x;
    int v[4];
    int sum = 0;
    #pragma unroll
    for (int u = 0; u < 4; ++u) {
        int idx = t * 4 + u;
        v[u] = (idx < nbkt) ? bktCnt[idx] : 0;
        sum += v[u];
    }
    part[t] = sum;
    __syncthreads();
    for (int off = 1; off < 256; off <<= 1) {
        int x = 0;
        if (t >= off) x = part[t - off];
        __syncthreads();
        part[t] += x;
        __syncthreads();
    }
    int run = (t == 0) ? 0 : part[t - 1];
    #pragma unroll
    for (int u = 0; u < 4; ++u) {
        int idx = t * 4 + u;
        if (idx < nbkt) base[idx] = run;
        run += v[u];
    }
    if (t == 0) base[nbkt] = e;
}

__global__ void __launch_bounds__(256) k_scatter(
    const int* __restrict__ DST, const int* __restrict__ SRC,
    const float* __restrict__ DIST, const float* __restrict__ EF,
    const int* __restrict__ hist, const int* __restrict__ base,
    float2* __restrict__ payA, float* __restrict__ ef_s,
    int e, int nbkt, int shift, int epb)
{
    __shared__ int loff[512];
    int b = blockIdx.x;
    for (int c = threadIdx.x; c < nbkt; c += blockDim.x)
        loff[c] = base[c] + hist[(size_t)c * NHB + b];
    __syncthreads();
    int i0 = b * epb, i1 = min(i0 + epb, e);
    if (i0 >= i1) return;
    int mask = (1 << shift) - 1;
    int nq = (i1 - i0) >> 2;
    const iv4* D4 = reinterpret_cast<const iv4*>(DST + i0);
    const iv4* S4 = reinterpret_cast<const iv4*>(SRC + i0);
    const fv4* T4 = reinterpret_cast<const fv4*>(DIST + i0);
    const fv4* F4 = reinterpret_cast<const fv4*>(EF + i0);
    for (int q = threadIdx.x; q < nq; q += blockDim.x) {
        iv4 dv = __builtin_nontemporal_load(D4 + q);
        iv4 sv = __builtin_nontemporal_load(S4 + q);
        fv4 tv = __builtin_nontemporal_load(T4 + q);
        fv4 fv = __builtin_nontemporal_load(F4 + q);
        #pragma unroll
        for (int u = 0; u < 4; ++u) {
            int d = dv[u];
            int c = d >> shift;
            int pos = atomicAdd(&loff[c], 1);
            int sd = (sv[u] << shift) | (d & mask);
            payA[pos] = make_float2(__int_as_float(sd), tv[u]);
            ef_s[pos] = fv[u];
        }
    }
    for (int i = i0 + 4 * nq + threadIdx.x; i < i1; i += blockDim.x) {
        int d = DST[i];
        int c = d >> shift;
        int pos = atomicAdd(&loff[c], 1);
        int sd = (SRC[i] << shift) | (d & mask);
        payA[pos] = make_float2(__int_as_float(sd), DIST[i]);
        ef_s[pos] = EF[i];
    }
}

// ============================ node encoder =================================

__global__ void __launch_bounds__(256) k_enc(
    const float* __restrict__ X, const float* __restrict__ W1,
    const float* __restrict__ B1, const float* __restrict__ W2,
    const float* __restrict__ B2, float* __restrict__ H0, int n)
{
    __shared__ float4 w1s[2048];
    for (int t = threadIdx.x; t < 2048; t += blockDim.x)
        w1s[t] = reinterpret_cast<const float4*>(W1)[t];
    __syncthreads();

    int i = blockIdx.x * blockDim.x + threadIdx.x;
    if (i >= n) return;

    const float4* xp = reinterpret_cast<const float4*>(X) + (size_t)i * 32;

    float acc[64];
    #pragma unroll
    for (int j = 0; j < 64; ++j) acc[j] = B1[j];

    for (int k4 = 0; k4 < 32; ++k4) {
        float4 xv = xp[k4];
        #pragma unroll
        for (int kk = 0; kk < 4; ++kk) {
            float x = (&xv.x)[kk];
            const float4* wrow = &w1s[(k4 * 4 + kk) * 16];
            #pragma unroll
            for (int j4 = 0; j4 < 16; ++j4) {
                float4 w = wrow[j4];
                acc[j4*4+0] = fmaf(x, w.x, acc[j4*4+0]);
                acc[j4*4+1] = fmaf(x, w.y, acc[j4*4+1]);
                acc[j4*4+2] = fmaf(x, w.z, acc[j4*4+2]);
                acc[j4*4+3] = fmaf(x, w.w, acc[j4*4+3]);
            }
        }
    }
    float o = B2[0];
    #pragma unroll
    for (int j = 0; j < 64; ++j)
        o = fmaf(fmaxf(acc[j], 0.f), W2[j], o);
    H0[i] = fmaxf(o, 0.f);
}

// ==================== bucketed edge passes (G-split) =======================
// partial layout: p[((c*G + g) << shift) + t]

__global__ void __launch_bounds__(256) k_passA(
    const float2* __restrict__ payA, const float* __restrict__ H0,
    const int* __restrict__ base,
    float* __restrict__ pSum, float* __restrict__ pNum, int shift, int G)
{
    __shared__ float lsum[512], lnum[512];
    int c = blockIdx.x / G, g = blockIdx.x % G;
    int bw = 1 << shift, mask = bw - 1;
    for (int t = threadIdx.x; t < bw; t += blockDim.x) { lsum[t] = 0.f; lnum[t] = 0.f; }
    __syncthreads();
    int b0 = base[c], len = base[c + 1] - b0;
    int i0 = b0 + (int)(((long long)len * g) / G);
    int i1 = b0 + (int)(((long long)len * (g + 1)) / G);
    const int T = blockDim.x;
    for (int i = i0 + (int)threadIdx.x; i < i1; i += 2 * T) {
        int jb = i + T;
        fv2 p0 = __builtin_nontemporal_load(
            reinterpret_cast<const fv2*>(payA) + i);
        fv2 p1 = {0.f, 0.f};
        bool vb = jb < i1;
        if (vb) p1 = __builtin_nontemporal_load(
                    reinterpret_cast<const fv2*>(payA) + jb);
        int sd0 = __float_as_int(p0.x);
        int sd1 = __float_as_int(p1.x);
        float h0a = H0[sd0 >> shift];
        float h0b = vb ? H0[sd1 >> shift] : 0.f;
        float e0 = __expf(p0.y);
        float e1 = __expf(p1.y);
        atomicAdd(&lsum[sd0 & mask], e0);
        atomicAdd(&lnum[sd0 & mask], e0 * h0a);
        if (vb) {
            atomicAdd(&lsum[sd1 & mask], e1);
            atomicAdd(&lnum[sd1 & mask], e1 * h0b);
        }
    }
    __syncthreads();
    size_t po = (size_t)blockIdx.x << shift;
    for (int t = threadIdx.x; t < bw; t += blockDim.x) {
        pSum[po + t] = lsum[t];
        pNum[po + t] = lnum[t];
    }
}

__global__ void __launch_bounds__(256) k_finA(
    const float* __restrict__ pSum, const float* __restrict__ pNum,
    float* __restrict__ H1, int shift, int n, int G)
{
    int d = blockIdx.x * blockDim.x + threadIdx.x;
    if (d >= n) return;
    int c = d >> shift, t = d & ((1 << shift) - 1);
    size_t b = (size_t)c * G << shift;
    int bw = 1 << shift;
    float s = 0.f, m = 0.f;
    for (int g = 0; g < G; ++g) {
        s += pSum[b + (size_t)g * bw + t];
        m += pNum[b + (size_t)g * bw + t];
    }
    H1[d] = (s != 0.f) ? m / s : 0.f;
}

// passB main: edge MLP -> e2 (overwrites ef_s) + partial agg/s2.
// Packed 2xfp32 MLP + software-pipelined payload prefetch.
__global__ void __launch_bounds__(256) k_passB(
    const float2* __restrict__ payA, float* __restrict__ ef_s,
    const float* __restrict__ H1,
    const float* __restrict__ W1, const float* __restrict__ B1,
    const float* __restrict__ W2, const float* __restrict__ B2,
    const int* __restrict__ base,
    float* __restrict__ pAgg, float* __restrict__ pS2, int shift, int n, int G)
{
    __shared__ float h1loc[512], lagg[512], ls2[512];
    const fv2 ZERO2 = {0.f, 0.f};
    int bw = 1 << shift, mask = bw - 1;
    int c = blockIdx.x / G, g = blockIdx.x % G;
    int d0 = c << shift;
    for (int t = threadIdx.x; t < bw; t += blockDim.x) {
        int d = d0 + t;
        h1loc[t] = (d < n) ? H1[d] : 0.f;
        lagg[t] = 0.f;
        ls2[t] = 0.f;
    }
    __syncthreads();
    const float b2 = B2[0];
    int b0 = base[c], len = base[c + 1] - b0;
    int i0 = b0 + (int)(((long long)len * g) / G);
    int i1 = b0 + (int)(((long long)len * (g + 1)) / G);
    const int T = blockDim.x;

    int i = i0 + (int)threadIdx.x;
    fv2 pa[4]; float xf[4];
    #pragma unroll
    for (int u = 0; u < 4; ++u) {
        int j = i + u * T;
        pa[u] = ZERO2; xf[u] = 0.f;
        if (j < i1) {
            pa[u] = __builtin_nontemporal_load(
                reinterpret_cast<const fv2*>(payA) + j);
            xf[u] = __builtin_nontemporal_load(ef_s + j);
        }
    }
    while (i < i1) {
        int inext = i + 4 * T;
        // prefetch next chunk BEFORE the store/atomic phase of this chunk
        fv2 pb[4]; float xg[4];
        #pragma unroll
        for (int u = 0; u < 4; ++u) {
            int j = inext + u * T;
            pb[u] = ZERO2; xg[u] = 0.f;
            if (j < i1) {
                pb[u] = __builtin_nontemporal_load(
                    reinterpret_cast<const fv2*>(payA) + j);
                xg[u] = __builtin_nontemporal_load(ef_s + j);
            }
        }
        // gathers + packed MLP
        fv2 x0v[4], hsv[4], hdv[4], o2[4];
        int lo[4];
        #pragma unroll
        for (int u = 0; u < 4; ++u) {
            int sd = __float_as_int(pa[u].x);
            lo[u] = sd & mask;
            float hs = H1[sd >> shift];
            float hd = h1loc[lo[u]];
            fv2 xt; xt.x = xf[u]; xt.y = xf[u];
            x0v[u] = xt;
            fv2 ht; ht.x = hs; ht.y = hs;
            hsv[u] = ht;
            fv2 dt; dt.x = hd; dt.y = hd;
            hdv[u] = dt;
            o2[u] = ZERO2;
        }
        #pragma unroll 4
        for (int j = 0; j < 64; j += 2) {
            fv2 aj = *reinterpret_cast<const fv2*>(W1 + j);
            fv2 bj = *reinterpret_cast<const fv2*>(W1 + 64 + j);
            fv2 cj = *reinterpret_cast<const fv2*>(W1 + 128 + j);
            fv2 dj = *reinterpret_cast<const fv2*>(B1 + j);
            fv2 vj = *reinterpret_cast<const fv2*>(W2 + j);
            #pragma unroll
            for (int u = 0; u < 4; ++u) {
                fv2 t = FMA2(x0v[u], aj,
                         FMA2(hsv[u], bj, FMA2(hdv[u], cj, dj)));
                t = MAX2(t, ZERO2);
                o2[u] = FMA2(t, vj, o2[u]);
            }
        }
        #pragma unroll
        for (int u = 0; u < 4; ++u) {
            int j = i + u * T;
            if (j < i1) {
                float eh = fmaxf(o2[u].x + o2[u].y + b2, 0.f);
                float ex = __expf(eh);
                ef_s[j] = ex;
                atomicAdd(&lagg[lo[u]], eh);
                atomicAdd(&ls2[lo[u]], ex);
            }
        }
        i = inext;
        #pragma unroll
        for (int u = 0; u < 4; ++u) { pa[u] = pb[u]; xf[u] = xg[u]; }
    }
    __syncthreads();
    size_t po = (size_t)blockIdx.x << shift;
    for (int t = threadIdx.x; t < bw; t += blockDim.x) {
        pAgg[po + t] = lagg[t];
        pS2[po + t] = ls2[t];
    }
}

// finB: sum partials; H2 = nuMLP(agg, h1); S2
__global__ void __launch_bounds__(256) k_finB(
    const float* __restrict__ pAgg, const float* __restrict__ pS2,
    const float* __restrict__ H1,
    const float* __restrict__ NW1, const float* __restrict__ NB1,
    const float* __restrict__ NW2, const float* __restrict__ NB2,
    float* __restrict__ H2, float* __restrict__ S2, int shift, int n, int G)
{
    int d = blockIdx.x * blockDim.x + threadIdx.x;
    if (d >= n) return;
    int c = d >> shift, t = d & ((1 << shift) - 1);
    size_t b = (size_t)c * G << shift;
    int bw = 1 << shift;
    float agg = 0.f, s2 = 0.f;
    for (int g = 0; g < G; ++g) {
        agg += pAgg[b + (size_t)g * bw + t];
        s2  += pS2[b + (size_t)g * bw + t];
    }
    float xh = H1[d];
    float o = NB2[0];
    #pragma unroll 4
    for (int j = 0; j < 64; ++j) {
        float a = fmaf(agg, NW1[j], fmaf(xh, NW1[64 + j], NB1[j]));
        o = fmaf(fmaxf(a, 0.f), NW2[j], o);
    }
    H2[d] = fmaxf(o, 0.f);
    S2[d] = s2;
}

// passC main: partial num2 (2-edge ILP)
__global__ void __launch_bounds__(256) k_passC(
    const float2* __restrict__ payA, const float* __restrict__ e2_s,
    const float* __restrict__ H2, const int* __restrict__ base,
    float* __restrict__ pNum, int shift, int G)
{
    __shared__ float lnum[512];
    int c = blockIdx.x / G, g = blockIdx.x % G;
    int bw = 1 << shift, mask = bw - 1;
    for (int t = threadIdx.x; t < bw; t += blockDim.x) lnum[t] = 0.f;
    __syncthreads();
    int b0 = base[c], len = base[c + 1] - b0;
    int i0 = b0 + (int)(((long long)len * g) / G);
    int i1 = b0 + (int)(((long long)len * (g + 1)) / G);
    const int T = blockDim.x;
    for (int i = i0 + (int)threadIdx.x; i < i1; i += 2 * T) {
        int jb = i + T;
        bool vb = jb < i1;
        fv2 p0 = __builtin_nontemporal_load(
            reinterpret_cast<const fv2*>(payA) + i);
        float e0 = __builtin_nontemporal_load(e2_s + i);
        fv2 p1 = {0.f, 0.f};
        float e1 = 0.f;
        if (vb) {
            p1 = __builtin_nontemporal_load(
                reinterpret_cast<const fv2*>(payA) + jb);
            e1 = __builtin_nontemporal_load(e2_s + jb);
        }
        int sd0 = __float_as_int(p0.x);
        int sd1 = __float_as_int(p1.x);
        float m0 = e0 * H2[sd0 >> shift];
        float m1 = vb ? e1 * H2[sd1 >> shift] : 0.f;
        atomicAdd(&lnum[sd0 & mask], m0);
        if (vb) atomicAdd(&lnum[sd1 & mask], m1);
    }
    __syncthreads();
    size_t po = (size_t)blockIdx.x << shift;
    for (int t = threadIdx.x; t < bw; t += blockDim.x)
        pNum[po + t] = lnum[t];
}

// finC: sum partials; OUT = decMLP(num2/s2)
__global__ void __launch_bounds__(256) k_finC(
    const float* __restrict__ pNum, const float* __restrict__ S2,
    const float* __restrict__ W1, const float* __restrict__ B1,
    const float* __restrict__ W2, const float* __restrict__ B2,
    float* __restrict__ OUT, int shift, int n, int G)
{
    int d = blockIdx.x * blockDim.x + threadIdx.x;
    if (d >= n) return;
    int c = d >> shift, t = d & ((1 << shift) - 1);
    size_t b = (size_t)c * G << shift;
    int bw = 1 << shift;
    float m = 0.f;
    for (int g = 0; g < G; ++g) m += pNum[b + (size_t)g * bw + t];
    float s = S2[d];
    float x = (s != 0.f) ? m / s : 0.f;
    float o = B2[0];
    #pragma unroll 4
    for (int j = 0; j < 64; ++j) {
        float a = fmaf(x, W1[j], B1[j]);
        o = fmaf(fmaxf(a, 0.f), W2[j], o);
    }
    OUT[d] = fmaxf(o, 0.f);
}

// ===================== fallback (atomic path) ==============================

__device__ __forceinline__ void atomAddF(float* p, float v) { unsafeAtomicAdd(p, v); }

__global__ void k_zero(float* __restrict__ p, int n) {
    int i = blockIdx.x * blockDim.x + threadIdx.x;
    if (i < n) p[i] = 0.f;
}

__global__ void __launch_bounds__(256) k_agg1(
    const float* __restrict__ DIST, const int* __restrict__ SRC,
    const int* __restrict__ DST, const float* __restrict__ H0,
    float* __restrict__ S1, float* __restrict__ NUM1, int e)
{
    int i = blockIdx.x * blockDim.x + threadIdx.x;
    if (i >= e) return;
    float ev = __expf(DIST[i]);
    atomAddF(&S1[DST[i]], ev);
    atomAddF(&NUM1[DST[i]], ev * H0[SRC[i]]);
}

__global__ void k_div(const float* __restrict__ NUM, const float* __restrict__ S,
                      float* __restrict__ H, int n) {
    int i = blockIdx.x * blockDim.x + threadIdx.x;
    if (i < n) {
        float s = S[i];
        H[i] = (s != 0.f) ? NUM[i] / s : 0.f;
    }
}

__global__ void __launch_bounds__(256) k_edgeF(
    const float* __restrict__ EF, const int* __restrict__ SRC,
    const int* __restrict__ DST, const float* __restrict__ H1,
    const float* __restrict__ W1, const float* __restrict__ B1,
    const float* __restrict__ W2, const float* __restrict__ B2,
    float* __restrict__ E2, float* __restrict__ AGG, float* __restrict__ S2, int e)
{
    int i = blockIdx.x * blockDim.x + threadIdx.x;
    if (i >= e) return;
    float x0 = EF[i];
    int s = SRC[i], d = DST[i];
    float h_s = H1[s], h_d = H1[d];
    float o = B2[0];
    for (int j = 0; j < 64; ++j) {
        float aj = fmaf(x0, W1[j], fmaf(h_s, W1[64+j], fmaf(h_d, W1[128+j], B1[j])));
        o = fmaf(fmaxf(aj, 0.f), W2[j], o);
    }
    float eh = fmaxf(o, 0.f);
    float ex = __expf(eh);
    E2[i] = ex;
    atomAddF(&AGG[d], eh);
    atomAddF(&S2[d], ex);
}

__global__ void k_nu(const float* __restrict__ AGG, const float* __restrict__ H1,
                     const float* __restrict__ W1, const float* __restrict__ B1,
                     const float* __restrict__ W2, const float* __restrict__ B2,
                     float* __restrict__ H2, int n)
{
    int i = blockIdx.x * blockDim.x + threadIdx.x;
    if (i >= n) return;
    float x0 = AGG[i], x1 = H1[i];
    float o = B2[0];
    #pragma unroll
    for (int j = 0; j < 64; ++j) {
        float a = fmaf(x0, W1[j], fmaf(x1, W1[64 + j], B1[j]));
        o = fmaf(fmaxf(a, 0.f), W2[j], o);
    }
    H2[i] = fmaxf(o, 0.f);
}

__global__ void __launch_bounds__(256) k_agg2F(
    const float* __restrict__ E2, const int* __restrict__ SRC,
    const int* __restrict__ DST, const float* __restrict__ H2,
    float* __restrict__ NUM2, int e)
{
    int i = blockIdx.x * blockDim.x + threadIdx.x;
    if (i >= e) return;
    atomAddF(&NUM2[DST[i]], E2[i] * H2[SRC[i]]);
}

__global__ void k_final(const float* __restrict__ NUM2, const float* __restrict__ S2,
                        const float* __restrict__ W1, const float* __restrict__ B1,
                        const float* __restrict__ W2, const float* __restrict__ B2,
                        float* __restrict__ OUT, int n)
{
    int i = blockIdx.x * blockDim.x + threadIdx.x;
    if (i >= n) return;
    float s = S2[i];
    float x = (s != 0.f) ? NUM2[i] / s : 0.f;
    float o = B2[0];
    #pragma unroll
    for (int j = 0; j < 64; ++j) {
        float a = fmaf(x, W1[j], B1[j]);
        o = fmaf(fmaxf(a, 0.f), W2[j], o);
    }
    OUT[i] = fmaxf(o, 0.f);
}

// ============================ launch =======================================

extern "C" void kernel_launch(void* const* d_in, const int* in_sizes, int n_in,
                              void* d_out, int out_size, void* d_ws, size_t ws_size,
                              hipStream_t stream)
{
    const float* node_feat = (const float*)d_in[0];
    const float* edge_feat = (const float*)d_in[1];
    const float* edge_dist = (const float*)d_in[2];
    const int*   src       = (const int*)d_in[3];
    const int*   dst       = (const int*)d_in[4];
    const float* enc_w1 = (const float*)d_in[5];
    const float* enc_b1 = (const float*)d_in[6];
    const float* enc_w2 = (const float*)d_in[7];
    const float* enc_b2 = (const float*)d_in[8];
    const float* nu_w1  = (const float*)d_in[9];
    const float* nu_b1  = (const float*)d_in[10];
    const float* nu_w2  = (const float*)d_in[11];
    const float* nu_b2  = (const float*)d_in[12];
    const float* eu_w1  = (const float*)d_in[13];
    const float* eu_b1  = (const float*)d_in[14];
    const float* eu_w2  = (const float*)d_in[15];
    const float* eu_b2  = (const float*)d_in[16];
    const float* dec_w1 = (const float*)d_in[17];
    const float* dec_b1 = (const float*)d_in[18];
    const float* dec_w2 = (const float*)d_in[19];
    const float* dec_b2 = (const float*)d_in[20];

    const int n = in_sizes[0] / 128;
    const int e = in_sizes[1];
    const int B = 256;

    int shift = 9;
    while ((((n + (1 << shift) - 1) >> shift) > 512) && shift < 12) shift++;
    const int nbkt = (n + (1 << shift) - 1) >> shift;
    int epb = (e + NHB - 1) / NHB;
    epb = (epb + 3) & ~3;

    // ws layout (4B words): h0,h1,h2,s2 [4n] | base[nbkt+1] bktCnt[nbkt]
    // hist[nbkt*NHB] | pad8 | payA[2e] | ef_s[e] | pP0 | pP1
    float* ws = (float*)d_ws;
    size_t w = (size_t)4 * n;
    int* base   = (int*)(ws + w); w += nbkt + 1;
    int* bktCnt = (int*)(ws + w); w += nbkt;
    int* hist   = (int*)(ws + w); w += (size_t)nbkt * NHB;
    w = (w + 1) & ~(size_t)1;
    float2* payA = (float2*)(ws + w); w += (size_t)2 * e;
    float* ef_s  = ws + w; w += e;

    // pick largest G in {16,8,4,2,1} whose partial arrays fit the workspace
    int G = 16;
    size_t psz;
    size_t need;
    for (;;) {
        psz = ((size_t)nbkt * G) << shift;
        need = (w + 2 * psz) * 4;
        if (need <= ws_size || G == 1) break;
        G >>= 1;
    }
    float* pP0 = ws + w;
    float* pP1 = ws + w + psz;

    float* h0 = ws;
    float* h1 = ws + (size_t)1 * n;
    float* h2 = ws + (size_t)2 * n;
    float* s2 = ws + (size_t)3 * n;

    if (ws_size >= need && nbkt <= 512 && (1 << shift) <= 512 &&
        ((size_t)n << shift) < (1u << 30)) {
        const int gE = nbkt * G;
        hipLaunchKernelGGL(k_chist, dim3(NHB), dim3(B), 0, stream,
                           dst, hist, e, nbkt, shift, epb);
        hipLaunchKernelGGL(k_scanA, dim3(nbkt), dim3(B), 0, stream, hist, bktCnt);
        hipLaunchKernelGGL(k_scanB, dim3(1), dim3(B), 0, stream, bktCnt, base, nbkt, e);
        hipLaunchKernelGGL(k_scatter, dim3(NHB), dim3(B), 0, stream,
                           dst, src, edge_dist, edge_feat, hist, base,
                           payA, ef_s, e, nbkt, shift, epb);
        hipLaunchKernelGGL(k_enc, dim3((n + B - 1) / B), dim3(B), 0, stream,
                           node_feat, enc_w1, enc_b1, enc_w2, enc_b2, h0, n);
        hipLaunchKernelGGL(k_passA, dim3(gE), dim3(B), 0, stream,
                           payA, h0, base, pP0, pP1, shift, G);
        hipLaunchKernelGGL(k_finA, dim3((n + B - 1) / B), dim3(B), 0, stream,
                           pP0, pP1, h1, shift, n, G);
        hipLaunchKernelGGL(k_passB, dim3(gE), dim3(B), 0, stream,
                           payA, ef_s, h1, eu_w1, eu_b1, eu_w2, eu_b2, base,
                           pP0, pP1, shift, n, G);
        hipLaunchKernelGGL(k_finB, dim3((n + B - 1) / B), dim3(B), 0, stream,
                           pP0, pP1, h1, nu_w1, nu_b1, nu_w2, nu_b2, h2, s2,
                           shift, n, G);
        hipLaunchKernelGGL(k_passC, dim3(gE), dim3(B), 0, stream,
                           payA, ef_s /*e2*/, h2, base, pP0, shift, G);
        hipLaunchKernelGGL(k_finC, dim3((n + B - 1) / B), dim3(B), 0, stream,
                           pP0, s2, dec_w1, dec_b1, dec_w2, dec_b2,
                           (float*)d_out, shift, n, G);
    } else {
        // fallback: atomic path (needs 8n + e floats)
        float* agg  = ws + (size_t)2 * n;
        float* s1   = ws + (size_t)4 * n;
        float* num1 = ws + (size_t)5 * n;
        float* num2 = ws + (size_t)6 * n;
        float* h2f  = ws + (size_t)7 * n;
        float* e2   = ws + (size_t)8 * n;
        hipLaunchKernelGGL(k_zero, dim3((5 * n + B - 1) / B), dim3(B), 0, stream,
                           agg, 5 * n);
        hipLaunchKernelGGL(k_enc, dim3((n + B - 1) / B), dim3(B), 0, stream,
                           node_feat, enc_w1, enc_b1, enc_w2, enc_b2, h0, n);
        hipLaunchKernelGGL(k_agg1, dim3((e + B - 1) / B), dim3(B), 0, stream,
                           edge_dist, src, dst, h0, s1, num1, e);
        hipLaunchKernelGGL(k_div, dim3((n + B - 1) / B), dim3(B), 0, stream,
                           num1, s1, h1, n);
        hipLaunchKernelGGL(k_edgeF, dim3((e + B - 1) / B), dim3(B), 0, stream,
                           edge_feat, src, dst, h1, eu_w1, eu_b1, eu_w2, eu_b2,
                           e2, agg, s2, e);
        hipLaunchKernelGGL(k_nu, dim3((n + B - 1) / B), dim3(B), 0, stream,
                           agg, h1, nu_w1, nu_b1, nu_w2, nu_b2, h2f, n);
        hipLaunchKernelGGL(k_agg2F, dim3((e + B - 1) / B), dim3(B), 0, stream,
                           e2, src, dst, h2f, num2, e);
        hipLaunchKernelGGL(k_final, dim3((n + B - 1) / B), dim3(B), 0, stream,
                           num2, s2, dec_w1, dec_b1, dec_w2, dec_b2, (float*)d_out, n);
    }
}

// Round 10
// 385.758 us; speedup vs baseline: 4.9246x; 1.0304x over previous
//
#include <hip/hip_runtime.h>

// ---------------------------------------------------------------------------
// GraphElementNetwork forward, bucketed path v9:
//  - k_chist / k_scatter now 1024-thread blocks (NHB=256 blocks kept):
//    v8 scatter was latency-bound at 9.8% occupancy (1 block/CU, dependent
//    LDS-atomic->store chains). Open-line set scales with #blocks, not
//    threads, so 4x waves at the same L2 footprint.
//  - passB: packed 2xfp32 MLP + software prefetch (v8); weights wave-uniform
//    scalar loads (v6 lesson); shift=9; G auto {16,8,4,2,1}.
// ---------------------------------------------------------------------------

#define NHB 256   // histogram / scatter blocks

typedef int   iv4 __attribute__((ext_vector_type(4)));
typedef float fv4 __attribute__((ext_vector_type(4)));
typedef float fv2 __attribute__((ext_vector_type(2)));

#if __has_builtin(__builtin_elementwise_fma)
#define FMA2(a, b, c) __builtin_elementwise_fma((a), (b), (c))
#else
static __device__ __forceinline__ fv2 FMA2(fv2 a, fv2 b, fv2 c) {
    fv2 r; r.x = fmaf(a.x, b.x, c.x); r.y = fmaf(a.y, b.y, c.y); return r;
}
#endif
#if __has_builtin(__builtin_elementwise_max)
#define MAX2(a, b) __builtin_elementwise_max((a), (b))
#else
static __device__ __forceinline__ fv2 MAX2(fv2 a, fv2 b) {
    fv2 r; r.x = fmaxf(a.x, b.x); r.y = fmaxf(a.y, b.y); return r;
}
#endif

// ============================ bucketing ====================================

__global__ void __launch_bounds__(1024) k_chist(
    const int* __restrict__ DST, int* __restrict__ hist,
    int e, int nbkt, int shift, int epb)
{
    __shared__ int lh[512];
    for (int c = threadIdx.x; c < nbkt; c += blockDim.x) lh[c] = 0;
    __syncthreads();
    int b = blockIdx.x;
    int i0 = b * epb, i1 = min(i0 + epb, e);
    int nq = (i1 > i0) ? ((i1 - i0) >> 2) : 0;
    const iv4* D4 = reinterpret_cast<const iv4*>(DST + i0);
    for (int q = threadIdx.x; q < nq; q += blockDim.x) {
        iv4 d = D4[q];
        atomicAdd(&lh[d.x >> shift], 1);
        atomicAdd(&lh[d.y >> shift], 1);
        atomicAdd(&lh[d.z >> shift], 1);
        atomicAdd(&lh[d.w >> shift], 1);
    }
    for (int i = i0 + 4 * nq + threadIdx.x; i < i1; i += blockDim.x)
        atomicAdd(&lh[DST[i] >> shift], 1);
    __syncthreads();
    for (int c = threadIdx.x; c < nbkt; c += blockDim.x)
        hist[(size_t)c * NHB + b] = lh[c];
}

__global__ void __launch_bounds__(256) k_scanA(
    int* __restrict__ hist, int* __restrict__ bktCnt)
{
    int c = blockIdx.x;
    int* row = hist + (size_t)c * NHB;
    __shared__ int part[256];
    int t = threadIdx.x;
    int v = row[t];
    part[t] = v;
    __syncthreads();
    for (int off = 1; off < 256; off <<= 1) {
        int x = 0;
        if (t >= off) x = part[t - off];
        __syncthreads();
        part[t] += x;
        __syncthreads();
    }
    if (t == 255) bktCnt[c] = part[255];
    row[t] = part[t] - v;
}

__global__ void __launch_bounds__(256) k_scanB(
    const int* __restrict__ bktCnt, int* __restrict__ base, int nbkt, int e)
{
    __shared__ int part[256];
    int t = threadIdx.x;
    int v[4];
    int sum = 0;
    #pragma unroll
    for (int u = 0; u < 4; ++u) {
        int idx = t * 4 + u;
        v[u] = (idx < nbkt) ? bktCnt[idx] : 0;
        sum += v[u];
    }
    part[t] = sum;
    __syncthreads();
    for (int off = 1; off < 256; off <<= 1) {
        int x = 0;
        if (t >= off) x = part[t - off];
        __syncthreads();
        part[t] += x;
        __syncthreads();
    }
    int run = (t == 0) ? 0 : part[t - 1];
    #pragma unroll
    for (int u = 0; u < 4; ++u) {
        int idx = t * 4 + u;
        if (idx < nbkt) base[idx] = run;
        run += v[u];
    }
    if (t == 0) base[nbkt] = e;
}

__global__ void __launch_bounds__(1024) k_scatter(
    const int* __restrict__ DST, const int* __restrict__ SRC,
    const float* __restrict__ DIST, const float* __restrict__ EF,
    const int* __restrict__ hist, const int* __restrict__ base,
    float2* __restrict__ payA, float* __restrict__ ef_s,
    int e, int nbkt, int shift, int epb)
{
    __shared__ int loff[512];
    int b = blockIdx.x;
    for (int c = threadIdx.x; c < nbkt; c += blockDim.x)
        loff[c] = base[c] + hist[(size_t)c * NHB + b];
    __syncthreads();
    int i0 = b * epb, i1 = min(i0 + epb, e);
    if (i0 >= i1) return;
    int mask = (1 << shift) - 1;
    int nq = (i1 - i0) >> 2;
    const iv4* D4 = reinterpret_cast<const iv4*>(DST + i0);
    const iv4* S4 = reinterpret_cast<const iv4*>(SRC + i0);
    const fv4* T4 = reinterpret_cast<const fv4*>(DIST + i0);
    const fv4* F4 = reinterpret_cast<const fv4*>(EF + i0);
    for (int q = threadIdx.x; q < nq; q += blockDim.x) {
        iv4 dv = __builtin_nontemporal_load(D4 + q);
        iv4 sv = __builtin_nontemporal_load(S4 + q);
        fv4 tv = __builtin_nontemporal_load(T4 + q);
        fv4 fv = __builtin_nontemporal_load(F4 + q);
        #pragma unroll
        for (int u = 0; u < 4; ++u) {
            int d = dv[u];
            int c = d >> shift;
            int pos = atomicAdd(&loff[c], 1);
            int sd = (sv[u] << shift) | (d & mask);
            payA[pos] = make_float2(__int_as_float(sd), tv[u]);
            ef_s[pos] = fv[u];
        }
    }
    for (int i = i0 + 4 * nq + threadIdx.x; i < i1; i += blockDim.x) {
        int d = DST[i];
        int c = d >> shift;
        int pos = atomicAdd(&loff[c], 1);
        int sd = (SRC[i] << shift) | (d & mask);
        payA[pos] = make_float2(__int_as_float(sd), DIST[i]);
        ef_s[pos] = EF[i];
    }
}

// ============================ node encoder =================================

__global__ void __launch_bounds__(256) k_enc(
    const float* __restrict__ X, const float* __restrict__ W1,
    const float* __restrict__ B1, const float* __restrict__ W2,
    const float* __restrict__ B2, float* __restrict__ H0, int n)
{
    __shared__ float4 w1s[2048];
    for (int t = threadIdx.x; t < 2048; t += blockDim.x)
        w1s[t] = reinterpret_cast<const float4*>(W1)[t];
    __syncthreads();

    int i = blockIdx.x * blockDim.x + threadIdx.x;
    if (i >= n) return;

    const float4* xp = reinterpret_cast<const float4*>(X) + (size_t)i * 32;

    float acc[64];
    #pragma unroll
    for (int j = 0; j < 64; ++j) acc[j] = B1[j];

    for (int k4 = 0; k4 < 32; ++k4) {
        float4 xv = xp[k4];
        #pragma unroll
        for (int kk = 0; kk < 4; ++kk) {
            float x = (&xv.x)[kk];
            const float4* wrow = &w1s[(k4 * 4 + kk) * 16];
            #pragma unroll
            for (int j4 = 0; j4 < 16; ++j4) {
                float4 w = wrow[j4];
                acc[j4*4+0] = fmaf(x, w.x, acc[j4*4+0]);
                acc[j4*4+1] = fmaf(x, w.y, acc[j4*4+1]);
                acc[j4*4+2] = fmaf(x, w.z, acc[j4*4+2]);
                acc[j4*4+3] = fmaf(x, w.w, acc[j4*4+3]);
            }
        }
    }
    float o = B2[0];
    #pragma unroll
    for (int j = 0; j < 64; ++j)
        o = fmaf(fmaxf(acc[j], 0.f), W2[j], o);
    H0[i] = fmaxf(o, 0.f);
}

// ==================== bucketed edge passes (G-split) =======================
// partial layout: p[((c*G + g) << shift) + t]

__global__ void __launch_bounds__(256) k_passA(
    const float2* __restrict__ payA, const float* __restrict__ H0,
    const int* __restrict__ base,
    float* __restrict__ pSum, float* __restrict__ pNum, int shift, int G)
{
    __shared__ float lsum[512], lnum[512];
    int c = blockIdx.x / G, g = blockIdx.x % G;
    int bw = 1 << shift, mask = bw - 1;
    for (int t = threadIdx.x; t < bw; t += blockDim.x) { lsum[t] = 0.f; lnum[t] = 0.f; }
    __syncthreads();
    int b0 = base[c], len = base[c + 1] - b0;
    int i0 = b0 + (int)(((long long)len * g) / G);
    int i1 = b0 + (int)(((long long)len * (g + 1)) / G);
    const int T = blockDim.x;
    for (int i = i0 + (int)threadIdx.x; i < i1; i += 2 * T) {
        int jb = i + T;
        fv2 p0 = __builtin_nontemporal_load(
            reinterpret_cast<const fv2*>(payA) + i);
        fv2 p1 = {0.f, 0.f};
        bool vb = jb < i1;
        if (vb) p1 = __builtin_nontemporal_load(
                    reinterpret_cast<const fv2*>(payA) + jb);
        int sd0 = __float_as_int(p0.x);
        int sd1 = __float_as_int(p1.x);
        float h0a = H0[sd0 >> shift];
        float h0b = vb ? H0[sd1 >> shift] : 0.f;
        float e0 = __expf(p0.y);
        float e1 = __expf(p1.y);
        atomicAdd(&lsum[sd0 & mask], e0);
        atomicAdd(&lnum[sd0 & mask], e0 * h0a);
        if (vb) {
            atomicAdd(&lsum[sd1 & mask], e1);
            atomicAdd(&lnum[sd1 & mask], e1 * h0b);
        }
    }
    __syncthreads();
    size_t po = (size_t)blockIdx.x << shift;
    for (int t = threadIdx.x; t < bw; t += blockDim.x) {
        pSum[po + t] = lsum[t];
        pNum[po + t] = lnum[t];
    }
}

__global__ void __launch_bounds__(256) k_finA(
    const float* __restrict__ pSum, const float* __restrict__ pNum,
    float* __restrict__ H1, int shift, int n, int G)
{
    int d = blockIdx.x * blockDim.x + threadIdx.x;
    if (d >= n) return;
    int c = d >> shift, t = d & ((1 << shift) - 1);
    size_t b = (size_t)c * G << shift;
    int bw = 1 << shift;
    float s = 0.f, m = 0.f;
    for (int g = 0; g < G; ++g) {
        s += pSum[b + (size_t)g * bw + t];
        m += pNum[b + (size_t)g * bw + t];
    }
    H1[d] = (s != 0.f) ? m / s : 0.f;
}

// passB main: edge MLP -> e2 (overwrites ef_s) + partial agg/s2.
// Packed 2xfp32 MLP + software-pipelined payload prefetch.
__global__ void __launch_bounds__(256) k_passB(
    const float2* __restrict__ payA, float* __restrict__ ef_s,
    const float* __restrict__ H1,
    const float* __restrict__ W1, const float* __restrict__ B1,
    const float* __restrict__ W2, const float* __restrict__ B2,
    const int* __restrict__ base,
    float* __restrict__ pAgg, float* __restrict__ pS2, int shift, int n, int G)
{
    __shared__ float h1loc[512], lagg[512], ls2[512];
    const fv2 ZERO2 = {0.f, 0.f};
    int bw = 1 << shift, mask = bw - 1;
    int c = blockIdx.x / G, g = blockIdx.x % G;
    int d0 = c << shift;
    for (int t = threadIdx.x; t < bw; t += blockDim.x) {
        int d = d0 + t;
        h1loc[t] = (d < n) ? H1[d] : 0.f;
        lagg[t] = 0.f;
        ls2[t] = 0.f;
    }
    __syncthreads();
    const float b2 = B2[0];
    int b0 = base[c], len = base[c + 1] - b0;
    int i0 = b0 + (int)(((long long)len * g) / G);
    int i1 = b0 + (int)(((long long)len * (g + 1)) / G);
    const int T = blockDim.x;

    int i = i0 + (int)threadIdx.x;
    fv2 pa[4]; float xf[4];
    #pragma unroll
    for (int u = 0; u < 4; ++u) {
        int j = i + u * T;
        pa[u] = ZERO2; xf[u] = 0.f;
        if (j < i1) {
            pa[u] = __builtin_nontemporal_load(
                reinterpret_cast<const fv2*>(payA) + j);
            xf[u] = __builtin_nontemporal_load(ef_s + j);
        }
    }
    while (i < i1) {
        int inext = i + 4 * T;
        // prefetch next chunk BEFORE the store/atomic phase of this chunk
        fv2 pb[4]; float xg[4];
        #pragma unroll
        for (int u = 0; u < 4; ++u) {
            int j = inext + u * T;
            pb[u] = ZERO2; xg[u] = 0.f;
            if (j < i1) {
                pb[u] = __builtin_nontemporal_load(
                    reinterpret_cast<const fv2*>(payA) + j);
                xg[u] = __builtin_nontemporal_load(ef_s + j);
            }
        }
        // gathers + packed MLP
        fv2 x0v[4], hsv[4], hdv[4], o2[4];
        int lo[4];
        #pragma unroll
        for (int u = 0; u < 4; ++u) {
            int sd = __float_as_int(pa[u].x);
            lo[u] = sd & mask;
            float hs = H1[sd >> shift];
            float hd = h1loc[lo[u]];
            fv2 xt; xt.x = xf[u]; xt.y = xf[u];
            x0v[u] = xt;
            fv2 ht; ht.x = hs; ht.y = hs;
            hsv[u] = ht;
            fv2 dt; dt.x = hd; dt.y = hd;
            hdv[u] = dt;
            o2[u] = ZERO2;
        }
        #pragma unroll 4
        for (int j = 0; j < 64; j += 2) {
            fv2 aj = *reinterpret_cast<const fv2*>(W1 + j);
            fv2 bj = *reinterpret_cast<const fv2*>(W1 + 64 + j);
            fv2 cj = *reinterpret_cast<const fv2*>(W1 + 128 + j);
            fv2 dj = *reinterpret_cast<const fv2*>(B1 + j);
            fv2 vj = *reinterpret_cast<const fv2*>(W2 + j);
            #pragma unroll
            for (int u = 0; u < 4; ++u) {
                fv2 t = FMA2(x0v[u], aj,
                         FMA2(hsv[u], bj, FMA2(hdv[u], cj, dj)));
                t = MAX2(t, ZERO2);
                o2[u] = FMA2(t, vj, o2[u]);
            }
        }
        #pragma unroll
        for (int u = 0; u < 4; ++u) {
            int j = i + u * T;
            if (j < i1) {
                float eh = fmaxf(o2[u].x + o2[u].y + b2, 0.f);
                float ex = __expf(eh);
                ef_s[j] = ex;
                atomicAdd(&lagg[lo[u]], eh);
                atomicAdd(&ls2[lo[u]], ex);
            }
        }
        i = inext;
        #pragma unroll
        for (int u = 0; u < 4; ++u) { pa[u] = pb[u]; xf[u] = xg[u]; }
    }
    __syncthreads();
    size_t po = (size_t)blockIdx.x << shift;
    for (int t = threadIdx.x; t < bw; t += blockDim.x) {
        pAgg[po + t] = lagg[t];
        pS2[po + t] = ls2[t];
    }
}

// finB: sum partials; H2 = nuMLP(agg, h1); S2
__global__ void __launch_bounds__(256) k_finB(
    const float* __restrict__ pAgg, const float* __restrict__ pS2,
    const float* __restrict__ H1,
    const float* __restrict__ NW1, const float* __restrict__ NB1,
    const float* __restrict__ NW2, const float* __restrict__ NB2,
    float* __restrict__ H2, float* __restrict__ S2, int shift, int n, int G)
{
    int d = blockIdx.x * blockDim.x + threadIdx.x;
    if (d >= n) return;
    int c = d >> shift, t = d & ((1 << shift) - 1);
    size_t b = (size_t)c * G << shift;
    int bw = 1 << shift;
    float agg = 0.f, s2 = 0.f;
    for (int g = 0; g < G; ++g) {
        agg += pAgg[b + (size_t)g * bw + t];
        s2  += pS2[b + (size_t)g * bw + t];
    }
    float xh = H1[d];
    float o = NB2[0];
    #pragma unroll 4
    for (int j = 0; j < 64; ++j) {
        float a = fmaf(agg, NW1[j], fmaf(xh, NW1[64 + j], NB1[j]));
        o = fmaf(fmaxf(a, 0.f), NW2[j], o);
    }
    H2[d] = fmaxf(o, 0.f);
    S2[d] = s2;
}

// passC main: partial num2 (2-edge ILP)
__global__ void __launch_bounds__(256) k_passC(
    const float2* __restrict__ payA, const float* __restrict__ e2_s,
    const float* __restrict__ H2, const int* __restrict__ base,
    float* __restrict__ pNum, int shift, int G)
{
    __shared__ float lnum[512];
    int c = blockIdx.x / G, g = blockIdx.x % G;
    int bw = 1 << shift, mask = bw - 1;
    for (int t = threadIdx.x; t < bw; t += blockDim.x) lnum[t] = 0.f;
    __syncthreads();
    int b0 = base[c], len = base[c + 1] - b0;
    int i0 = b0 + (int)(((long long)len * g) / G);
    int i1 = b0 + (int)(((long long)len * (g + 1)) / G);
    const int T = blockDim.x;
    for (int i = i0 + (int)threadIdx.x; i < i1; i += 2 * T) {
        int jb = i + T;
        bool vb = jb < i1;
        fv2 p0 = __builtin_nontemporal_load(
            reinterpret_cast<const fv2*>(payA) + i);
        float e0 = __builtin_nontemporal_load(e2_s + i);
        fv2 p1 = {0.f, 0.f};
        float e1 = 0.f;
        if (vb) {
            p1 = __builtin_nontemporal_load(
                reinterpret_cast<const fv2*>(payA) + jb);
            e1 = __builtin_nontemporal_load(e2_s + jb);
        }
        int sd0 = __float_as_int(p0.x);
        int sd1 = __float_as_int(p1.x);
        float m0 = e0 * H2[sd0 >> shift];
        float m1 = vb ? e1 * H2[sd1 >> shift] : 0.f;
        atomicAdd(&lnum[sd0 & mask], m0);
        if (vb) atomicAdd(&lnum[sd1 & mask], m1);
    }
    __syncthreads();
    size_t po = (size_t)blockIdx.x << shift;
    for (int t = threadIdx.x; t < bw; t += blockDim.x)
        pNum[po + t] = lnum[t];
}

// finC: sum partials; OUT = decMLP(num2/s2)
__global__ void __launch_bounds__(256) k_finC(
    const float* __restrict__ pNum, const float* __restrict__ S2,
    const float* __restrict__ W1, const float* __restrict__ B1,
    const float* __restrict__ W2, const float* __restrict__ B2,
    float* __restrict__ OUT, int shift, int n, int G)
{
    int d = blockIdx.x * blockDim.x + threadIdx.x;
    if (d >= n) return;
    int c = d >> shift, t = d & ((1 << shift) - 1);
    size_t b = (size_t)c * G << shift;
    int bw = 1 << shift;
    float m = 0.f;
    for (int g = 0; g < G; ++g) m += pNum[b + (size_t)g * bw + t];
    float s = S2[d];
    float x = (s != 0.f) ? m / s : 0.f;
    float o = B2[0];
    #pragma unroll 4
    for (int j = 0; j < 64; ++j) {
        float a = fmaf(x, W1[j], B1[j]);
        o = fmaf(fmaxf(a, 0.f), W2[j], o);
    }
    OUT[d] = fmaxf(o, 0.f);
}

// ===================== fallback (atomic path) ==============================

__device__ __forceinline__ void atomAddF(float* p, float v) { unsafeAtomicAdd(p, v); }

__global__ void k_zero(float* __restrict__ p, int n) {
    int i = blockIdx.x * blockDim.x + threadIdx.x;
    if (i < n) p[i] = 0.f;
}

__global__ void __launch_bounds__(256) k_agg1(
    const float* __restrict__ DIST, const int* __restrict__ SRC,
    const int* __restrict__ DST, const float* __restrict__ H0,
    float* __restrict__ S1, float* __restrict__ NUM1, int e)
{
    int i = blockIdx.x * blockDim.x + threadIdx.x;
    if (i >= e) return;
    float ev = __expf(DIST[i]);
    atomAddF(&S1[DST[i]], ev);
    atomAddF(&NUM1[DST[i]], ev * H0[SRC[i]]);
}

__global__ void k_div(const float* __restrict__ NUM, const float* __restrict__ S,
                      float* __restrict__ H, int n) {
    int i = blockIdx.x * blockDim.x + threadIdx.x;
    if (i < n) {
        float s = S[i];
        H[i] = (s != 0.f) ? NUM[i] / s : 0.f;
    }
}

__global__ void __launch_bounds__(256) k_edgeF(
    const float* __restrict__ EF, const int* __restrict__ SRC,
    const int* __restrict__ DST, const float* __restrict__ H1,
    const float* __restrict__ W1, const float* __restrict__ B1,
    const float* __restrict__ W2, const float* __restrict__ B2,
    float* __restrict__ E2, float* __restrict__ AGG, float* __restrict__ S2, int e)
{
    int i = blockIdx.x * blockDim.x + threadIdx.x;
    if (i >= e) return;
    float x0 = EF[i];
    int s = SRC[i], d = DST[i];
    float h_s = H1[s], h_d = H1[d];
    float o = B2[0];
    for (int j = 0; j < 64; ++j) {
        float aj = fmaf(x0, W1[j], fmaf(h_s, W1[64+j], fmaf(h_d, W1[128+j], B1[j])));
        o = fmaf(fmaxf(aj, 0.f), W2[j], o);
    }
    float eh = fmaxf(o, 0.f);
    float ex = __expf(eh);
    E2[i] = ex;
    atomAddF(&AGG[d], eh);
    atomAddF(&S2[d], ex);
}

__global__ void k_nu(const float* __restrict__ AGG, const float* __restrict__ H1,
                     const float* __restrict__ W1, const float* __restrict__ B1,
                     const float* __restrict__ W2, const float* __restrict__ B2,
                     float* __restrict__ H2, int n)
{
    int i = blockIdx.x * blockDim.x + threadIdx.x;
    if (i >= n) return;
    float x0 = AGG[i], x1 = H1[i];
    float o = B2[0];
    #pragma unroll
    for (int j = 0; j < 64; ++j) {
        float a = fmaf(x0, W1[j], fmaf(x1, W1[64 + j], B1[j]));
        o = fmaf(fmaxf(a, 0.f), W2[j], o);
    }
    H2[i] = fmaxf(o, 0.f);
}

__global__ void __launch_bounds__(256) k_agg2F(
    const float* __restrict__ E2, const int* __restrict__ SRC,
    const int* __restrict__ DST, const float* __restrict__ H2,
    float* __restrict__ NUM2, int e)
{
    int i = blockIdx.x * blockDim.x + threadIdx.x;
    if (i >= e) return;
    atomAddF(&NUM2[DST[i]], E2[i] * H2[SRC[i]]);
}

__global__ void k_final(const float* __restrict__ NUM2, const float* __restrict__ S2,
                        const float* __restrict__ W1, const float* __restrict__ B1,
                        const float* __restrict__ W2, const float* __restrict__ B2,
                        float* __restrict__ OUT, int n)
{
    int i = blockIdx.x * blockDim.x + threadIdx.x;
    if (i >= n) return;
    float s = S2[i];
    float x = (s != 0.f) ? NUM2[i] / s : 0.f;
    float o = B2[0];
    #pragma unroll
    for (int j = 0; j < 64; ++j) {
        float a = fmaf(x, W1[j], B1[j]);
        o = fmaf(fmaxf(a, 0.f), W2[j], o);
    }
    OUT[i] = fmaxf(o, 0.f);
}

// ============================ launch =======================================

extern "C" void kernel_launch(void* const* d_in, const int* in_sizes, int n_in,
                              void* d_out, int out_size, void* d_ws, size_t ws_size,
                              hipStream_t stream)
{
    const float* node_feat = (const float*)d_in[0];
    const float* edge_feat = (const float*)d_in[1];
    const float* edge_dist = (const float*)d_in[2];
    const int*   src       = (const int*)d_in[3];
    const int*   dst       = (const int*)d_in[4];
    const float* enc_w1 = (const float*)d_in[5];
    const float* enc_b1 = (const float*)d_in[6];
    const float* enc_w2 = (const float*)d_in[7];
    const float* enc_b2 = (const float*)d_in[8];
    const float* nu_w1  = (const float*)d_in[9];
    const float* nu_b1  = (const float*)d_in[10];
    const float* nu_w2  = (const float*)d_in[11];
    const float* nu_b2  = (const float*)d_in[12];
    const float* eu_w1  = (const float*)d_in[13];
    const float* eu_b1  = (const float*)d_in[14];
    const float* eu_w2  = (const float*)d_in[15];
    const float* eu_b2  = (const float*)d_in[16];
    const float* dec_w1 = (const float*)d_in[17];
    const float* dec_b1 = (const float*)d_in[18];
    const float* dec_w2 = (const float*)d_in[19];
    const float* dec_b2 = (const float*)d_in[20];

    const int n = in_sizes[0] / 128;
    const int e = in_sizes[1];
    const int B = 256;

    int shift = 9;
    while ((((n + (1 << shift) - 1) >> shift) > 512) && shift < 12) shift++;
    const int nbkt = (n + (1 << shift) - 1) >> shift;
    int epb = (e + NHB - 1) / NHB;
    epb = (epb + 3) & ~3;

    // ws layout (4B words): h0,h1,h2,s2 [4n] | base[nbkt+1] bktCnt[nbkt]
    // hist[nbkt*NHB] | pad8 | payA[2e] | ef_s[e] | pP0 | pP1
    float* ws = (float*)d_ws;
    size_t w = (size_t)4 * n;
    int* base   = (int*)(ws + w); w += nbkt + 1;
    int* bktCnt = (int*)(ws + w); w += nbkt;
    int* hist   = (int*)(ws + w); w += (size_t)nbkt * NHB;
    w = (w + 1) & ~(size_t)1;
    float2* payA = (float2*)(ws + w); w += (size_t)2 * e;
    float* ef_s  = ws + w; w += e;

    // pick largest G in {16,8,4,2,1} whose partial arrays fit the workspace
    int G = 16;
    size_t psz;
    size_t need;
    for (;;) {
        psz = ((size_t)nbkt * G) << shift;
        need = (w + 2 * psz) * 4;
        if (need <= ws_size || G == 1) break;
        G >>= 1;
    }
    float* pP0 = ws + w;
    float* pP1 = ws + w + psz;

    float* h0 = ws;
    float* h1 = ws + (size_t)1 * n;
    float* h2 = ws + (size_t)2 * n;
    float* s2 = ws + (size_t)3 * n;

    if (ws_size >= need && nbkt <= 512 && (1 << shift) <= 512 &&
        ((size_t)n << shift) < (1u << 30)) {
        const int gE = nbkt * G;
        hipLaunchKernelGGL(k_chist, dim3(NHB), dim3(1024), 0, stream,
                           dst, hist, e, nbkt, shift, epb);
        hipLaunchKernelGGL(k_scanA, dim3(nbkt), dim3(B), 0, stream, hist, bktCnt);
        hipLaunchKernelGGL(k_scanB, dim3(1), dim3(B), 0, stream, bktCnt, base, nbkt, e);
        hipLaunchKernelGGL(k_scatter, dim3(NHB), dim3(1024), 0, stream,
                           dst, src, edge_dist, edge_feat, hist, base,
                           payA, ef_s, e, nbkt, shift, epb);
        hipLaunchKernelGGL(k_enc, dim3((n + B - 1) / B), dim3(B), 0, stream,
                           node_feat, enc_w1, enc_b1, enc_w2, enc_b2, h0, n);
        hipLaunchKernelGGL(k_passA, dim3(gE), dim3(B), 0, stream,
                           payA, h0, base, pP0, pP1, shift, G);
        hipLaunchKernelGGL(k_finA, dim3((n + B - 1) / B), dim3(B), 0, stream,
                           pP0, pP1, h1, shift, n, G);
        hipLaunchKernelGGL(k_passB, dim3(gE), dim3(B), 0, stream,
                           payA, ef_s, h1, eu_w1, eu_b1, eu_w2, eu_b2, base,
                           pP0, pP1, shift, n, G);
        hipLaunchKernelGGL(k_finB, dim3((n + B - 1) / B), dim3(B), 0, stream,
                           pP0, pP1, h1, nu_w1, nu_b1, nu_w2, nu_b2, h2, s2,
                           shift, n, G);
        hipLaunchKernelGGL(k_passC, dim3(gE), dim3(B), 0, stream,
                           payA, ef_s /*e2*/, h2, base, pP0, shift, G);
        hipLaunchKernelGGL(k_finC, dim3((n + B - 1) / B), dim3(B), 0, stream,
                           pP0, s2, dec_w1, dec_b1, dec_w2, dec_b2,
                           (float*)d_out, shift, n, G);
    } else {
        // fallback: atomic path (needs 8n + e floats)
        float* agg  = ws + (size_t)2 * n;
        float* s1   = ws + (size_t)4 * n;
        float* num1 = ws + (size_t)5 * n;
        float* num2 = ws + (size_t)6 * n;
        float* h2f  = ws + (size_t)7 * n;
        float* e2   = ws + (size_t)8 * n;
        hipLaunchKernelGGL(k_zero, dim3((5 * n + B - 1) / B), dim3(B), 0, stream,
                           agg, 5 * n);
        hipLaunchKernelGGL(k_enc, dim3((n + B - 1) / B), dim3(B), 0, stream,
                           node_feat, enc_w1, enc_b1, enc_w2, enc_b2, h0, n);
        hipLaunchKernelGGL(k_agg1, dim3((e + B - 1) / B), dim3(B), 0, stream,
                           edge_dist, src, dst, h0, s1, num1, e);
        hipLaunchKernelGGL(k_div, dim3((n + B - 1) / B), dim3(B), 0, stream,
                           num1, s1, h1, n);
        hipLaunchKernelGGL(k_edgeF, dim3((e + B - 1) / B), dim3(B), 0, stream,
                           edge_feat, src, dst, h1, eu_w1, eu_b1, eu_w2, eu_b2,
                           e2, agg, s2, e);
        hipLaunchKernelGGL(k_nu, dim3((n + B - 1) / B), dim3(B), 0, stream,
                           agg, h1, nu_w1, nu_b1, nu_w2, nu_b2, h2f, n);
        hipLaunchKernelGGL(k_agg2F, dim3((e + B - 1) / B), dim3(B), 0, stream,
                           e2, src, dst, h2f, num2, e);
        hipLaunchKernelGGL(k_final, dim3((n + B - 1) / B), dim3(B), 0, stream,
                           num2, s2, dec_w1, dec_b1, dec_w2, dec_b2, (float*)d_out, n);
    }
}